// Round 7
// baseline (644.635 us; speedup 1.0000x reference)
//
#include <hip/hip_runtime.h>
#include <math.h>

#define N_NODES 100000
#define N_EDGES 1600000
#define NEG 0.2f
#define MAXDEG 128
#define WPB 4   // waves per block for per-node kernels

__device__ __forceinline__ float lrelu(float x){ return x > 0.f ? x : NEG*x; }
__device__ __forceinline__ unsigned short f2bf(float f){
  unsigned int u = __float_as_uint(f);
  u += 0x7FFFu + ((u >> 16) & 1u);   // RNE
  return (unsigned short)(u >> 16);
}

// ---------------- fused preprocessing + layer-0 GEMM ----------------
// R12: fuse atomic-latency-bound deg (84us @ 4% VALU) with the independent
// layer-0 GEMM as block roles in one dispatch. R12 result: serialized
// (122 = 84+38) because VGPR 72 / 27% occupancy starved the deg role's
// atomic concurrency. R13: 32-row GEMM tile (acc[2][8], VGPR target <=64 ->
// 32-wave/CU ceiling) + 2 edges/thread in deg role (2 atomics in flight).
// Grid = 6250: bid&1 selects role; 3125*512 edges / 3125*32 rows, both exact.
__global__ __launch_bounds__(256) void k_pre(const int* __restrict__ dst, const float* __restrict__ eatt,
    const float* __restrict__ We0, const float* __restrict__ ae0,
    const float* __restrict__ We1, const float* __restrict__ ae1,
    int* __restrict__ deg, int* __restrict__ rank, float2* __restrict__ ae01,
    const float* __restrict__ X, const float* __restrict__ W,
    const float* __restrict__ a_s, const float* __restrict__ a_d,
    unsigned short* __restrict__ Ybf, float* __restrict__ asrc, float* __restrict__ adst){
  __shared__ float Xs[16][36];
  __shared__ float Ws[16][128];
  __shared__ float as_s[128], ad_s[128];
  int t = threadIdx.x;
  int bid = blockIdx.x;
  if ((bid & 1) == 0){
    // ---- deg role: 512 edges, 2 per thread (2 independent atomics in flight) ----
    float* wea = &Ws[0][0];   // 32 floats staged in shared
    if (t < 32){
      const float* Wm = (t < 16) ? We0 : We1;
      const float* am = (t < 16) ? ae0 : ae1;
      int r = t & 15;
      float acc = 0.f;
      #pragma unroll
      for (int j=0;j<128;j++) acc += Wm[r*128+j]*am[j];
      wea[t] = acc;
    }
    __syncthreads();
    int e0 = (bid >> 1)*512 + t;
    int e1 = e0 + 256;
    const float4* pa = (const float4*)(eatt + (size_t)e0*16);
    const float4* pb = (const float4*)(eatt + (size_t)e1*16);
    float4 a0=pa[0], a1=pa[1], a2=pa[2], a3=pa[3];
    float4 b0=pb[0], b1=pb[1], b2=pb[2], b3=pb[3];
    // identical association order to the R6 dot -> bit-exact per edge
    float f0a = a0.x*wea[0] +a0.y*wea[1] +a0.z*wea[2] +a0.w*wea[3]
              + a1.x*wea[4] +a1.y*wea[5] +a1.z*wea[6] +a1.w*wea[7]
              + a2.x*wea[8] +a2.y*wea[9] +a2.z*wea[10]+a2.w*wea[11]
              + a3.x*wea[12]+a3.y*wea[13]+a3.z*wea[14]+a3.w*wea[15];
    float f1a = a0.x*wea[16]+a0.y*wea[17]+a0.z*wea[18]+a0.w*wea[19]
              + a1.x*wea[20]+a1.y*wea[21]+a1.z*wea[22]+a1.w*wea[23]
              + a2.x*wea[24]+a2.y*wea[25]+a2.z*wea[26]+a2.w*wea[27]
              + a3.x*wea[28]+a3.y*wea[29]+a3.z*wea[30]+a3.w*wea[31];
    float f0b = b0.x*wea[0] +b0.y*wea[1] +b0.z*wea[2] +b0.w*wea[3]
              + b1.x*wea[4] +b1.y*wea[5] +b1.z*wea[6] +b1.w*wea[7]
              + b2.x*wea[8] +b2.y*wea[9] +b2.z*wea[10]+b2.w*wea[11]
              + b3.x*wea[12]+b3.y*wea[13]+b3.z*wea[14]+b3.w*wea[15];
    float f1b = b0.x*wea[16]+b0.y*wea[17]+b0.z*wea[18]+b0.w*wea[19]
              + b1.x*wea[20]+b1.y*wea[21]+b1.z*wea[22]+b1.w*wea[23]
              + b2.x*wea[24]+b2.y*wea[25]+b2.z*wea[26]+b2.w*wea[27]
              + b3.x*wea[28]+b3.y*wea[29]+b3.z*wea[30]+b3.w*wea[31];
    int da = dst[e0], db = dst[e1];
    int ra = atomicAdd(&deg[da], 1);   // both issued before dependent stores
    int rb = atomicAdd(&deg[db], 1);
    rank[e0] = ra;
    rank[e1] = rb;
    ae01[e0] = make_float2(f0a, f1a);
    ae01[e1] = make_float2(f0b, f1b);
    return;
  }
  // ---- GEMM role: x@W0 -> Abf(bf16) + asrc/adst, 32-row tile (bid>>1) ----
  if (t < 128){ as_s[t] = a_s[t]; ad_s[t] = a_d[t]; }
  int row0 = (bid >> 1) * 32;
  int tc = t & 15, tr = t >> 4;
  int c0 = tc*8, r0 = tr*2;
  int lr = (t & 127) >> 2, lc = (t & 3) << 2;   // threads 0-127 stage X
  int wk = t >> 4, wc = (t & 15) * 8;
  float acc[2][8];
  #pragma unroll
  for (int i=0;i<2;i++)
    #pragma unroll
    for (int j=0;j<8;j++) acc[i][j]=0.f;
  for (int k0=0; k0<128; k0+=16){
    float4 xv = make_float4(0.f,0.f,0.f,0.f);
    if (t < 128) xv = *(const float4*)(X + (size_t)(row0+lr)*128 + k0 + lc);
    float4 wv0 = *(const float4*)(W + (size_t)(k0+wk)*128 + wc);
    float4 wv1 = *(const float4*)(W + (size_t)(k0+wk)*128 + wc + 4);
    __syncthreads();
    if (t < 128){
      Xs[lc+0][lr]=xv.x; Xs[lc+1][lr]=xv.y; Xs[lc+2][lr]=xv.z; Xs[lc+3][lr]=xv.w;
    }
    *(float4*)&Ws[wk][wc]   = wv0;
    *(float4*)&Ws[wk][wc+4] = wv1;
    __syncthreads();
    #pragma unroll
    for (int kk=0;kk<16;kk++){
      float a0v = Xs[kk][r0], a1v = Xs[kk][r0+1];
      float4 wb0 = *(const float4*)&Ws[kk][c0];
      float4 wb1 = *(const float4*)&Ws[kk][c0+4];
      float bv[8] = {wb0.x,wb0.y,wb0.z,wb0.w,wb1.x,wb1.y,wb1.z,wb1.w};
      #pragma unroll
      for (int j=0;j<8;j++){ acc[0][j] += a0v*bv[j]; acc[1][j] += a1v*bv[j]; }
    }
  }
  #pragma unroll
  for (int i=0;i<2;i++){
    int r = row0 + r0 + i;
    float v[8];
    #pragma unroll
    for (int j=0;j<8;j++) v[j] = acc[i][j];
    uint4 pk;
    pk.x = (unsigned)f2bf(v[0]) | ((unsigned)f2bf(v[1])<<16);
    pk.y = (unsigned)f2bf(v[2]) | ((unsigned)f2bf(v[3])<<16);
    pk.z = (unsigned)f2bf(v[4]) | ((unsigned)f2bf(v[5])<<16);
    pk.w = (unsigned)f2bf(v[6]) | ((unsigned)f2bf(v[7])<<16);
    *(uint4*)(Ybf + (size_t)r*128 + c0) = pk;
    float s=0.f, d=0.f;
    #pragma unroll
    for (int j=0;j<8;j++){ s += v[j]*as_s[c0+j]; d += v[j]*ad_s[c0+j]; }
    #pragma unroll
    for (int off=1; off<16; off<<=1){ s += __shfl_xor(s,off); d += __shfl_xor(d,off); }
    if ((t & 15)==0){ asrc[r]=s; adst[r]=d; }
  }
}

// ---------------- exclusive scan (3 phase) ----------------
__global__ __launch_bounds__(256) void k_scan_a(const int* __restrict__ deg, int* __restrict__ incl, int* __restrict__ bsum){
  __shared__ int s[256];
  int t = threadIdx.x; int i = blockIdx.x*256 + t;
  int v = (i < N_NODES) ? deg[i] : 0;
  s[t] = v; __syncthreads();
  for (int off=1; off<256; off<<=1){
    int u = (t>=off)? s[t-off] : 0; __syncthreads();
    s[t] += u; __syncthreads();
  }
  if (i < N_NODES) incl[i] = s[t];
  if (t == 255) bsum[blockIdx.x] = s[t];
}
__global__ __launch_bounds__(512) void k_scan_b(const int* __restrict__ bsum, int* __restrict__ bexcl, int nb){
  __shared__ int s[512];
  int t = threadIdx.x;
  int v = (t<nb)? bsum[t] : 0;
  s[t] = v; __syncthreads();
  for (int off=1; off<512; off<<=1){
    int u = (t>=off)? s[t-off] : 0; __syncthreads();
    s[t] += u; __syncthreads();
  }
  if (t<nb) bexcl[t] = s[t]-v;
}
__global__ __launch_bounds__(256) void k_scan_c(const int* __restrict__ incl, const int* __restrict__ deg,
    const int* __restrict__ bexcl, int* __restrict__ rowptr){
  int i = blockIdx.x*256+threadIdx.x;
  if (i < N_NODES) rowptr[i] = incl[i] - deg[i] + bexcl[blockIdx.x];
  if (i == 0) rowptr[N_NODES] = N_EDGES;
}

// ---------------- CSR fill: pure gather -> scatter ----------------
__global__ __launch_bounds__(256) void k_fillf(const int* __restrict__ src, const int* __restrict__ dst,
     const int* __restrict__ rank, const float2* __restrict__ ae01,
     const int* __restrict__ rowptr, uint4* __restrict__ csr){
  int e = blockIdx.x*256+threadIdx.x;
  if (e >= N_EDGES) return;
  int d = dst[e];
  float2 ae = ae01[e];
  int pos = rowptr[d] + rank[e];
  csr[pos] = make_uint4((unsigned)src[e], __float_as_uint(ae.x), __float_as_uint(ae.y), 0u);
}

// ---------------- fp32 GEMM + fused attention dots (layer 1) ----------------
__global__ __launch_bounds__(256) void k_gemm(const float* __restrict__ X, const float* __restrict__ W,
    const float* __restrict__ bias, float* __restrict__ Y, unsigned short* __restrict__ Ybf,
    const float* __restrict__ a_s, const float* __restrict__ a_d,
    float* __restrict__ asrc, float* __restrict__ adst, int M, int relu){
  __shared__ float Xs[16][68];
  __shared__ float Ws[16][128];
  __shared__ float as_s[128], ad_s[128];
  int t = threadIdx.x;
  if (a_s && t < 128){ as_s[t] = a_s[t]; ad_s[t] = a_d[t]; }
  int row0 = blockIdx.x * 64;
  int tc = t & 15, tr = t >> 4;
  int c0 = tc*8, r0 = tr*4;
  int lr = t >> 2, lc = (t & 3) << 2;
  int wk = t >> 4, wc = (t & 15) * 8;
  float acc[4][8];
  #pragma unroll
  for (int i=0;i<4;i++)
    #pragma unroll
    for (int j=0;j<8;j++) acc[i][j]=0.f;
  int gr = row0 + lr;
  for (int k0=0; k0<128; k0+=16){
    float4 xv = make_float4(0.f,0.f,0.f,0.f);
    if (gr < M) xv = *(const float4*)(X + (size_t)gr*128 + k0 + lc);
    float4 wv0 = *(const float4*)(W + (size_t)(k0+wk)*128 + wc);
    float4 wv1 = *(const float4*)(W + (size_t)(k0+wk)*128 + wc + 4);
    __syncthreads();
    Xs[lc+0][lr]=xv.x; Xs[lc+1][lr]=xv.y; Xs[lc+2][lr]=xv.z; Xs[lc+3][lr]=xv.w;
    *(float4*)&Ws[wk][wc]   = wv0;
    *(float4*)&Ws[wk][wc+4] = wv1;
    __syncthreads();
    #pragma unroll
    for (int kk=0;kk<16;kk++){
      float4 a  = *(const float4*)&Xs[kk][r0];
      float4 b0 = *(const float4*)&Ws[kk][c0];
      float4 b1 = *(const float4*)&Ws[kk][c0+4];
      float av[4] = {a.x,a.y,a.z,a.w};
      float bv[8] = {b0.x,b0.y,b0.z,b0.w,b1.x,b1.y,b1.z,b1.w};
      #pragma unroll
      for (int i=0;i<4;i++)
        #pragma unroll
        for (int j=0;j<8;j++) acc[i][j] += av[i]*bv[j];
    }
  }
  #pragma unroll
  for (int i=0;i<4;i++){
    int r = row0 + r0 + i;
    float v[8];
    #pragma unroll
    for (int j=0;j<8;j++){
      float u = acc[i][j] + (bias ? bias[c0+j] : 0.f);
      v[j] = relu ? fmaxf(u, 0.f) : u;
    }
    if (r < M){
      if (Y){
        *(float4*)(Y + (size_t)r*128 + c0)     = make_float4(v[0],v[1],v[2],v[3]);
        *(float4*)(Y + (size_t)r*128 + c0 + 4) = make_float4(v[4],v[5],v[6],v[7]);
      }
      if (Ybf){
        uint4 pk;
        pk.x = (unsigned)f2bf(v[0]) | ((unsigned)f2bf(v[1])<<16);
        pk.y = (unsigned)f2bf(v[2]) | ((unsigned)f2bf(v[3])<<16);
        pk.z = (unsigned)f2bf(v[4]) | ((unsigned)f2bf(v[5])<<16);
        pk.w = (unsigned)f2bf(v[6]) | ((unsigned)f2bf(v[7])<<16);
        *(uint4*)(Ybf + (size_t)r*128 + c0) = pk;
      }
    }
    if (a_s){
      float s=0.f, d=0.f;
      #pragma unroll
      for (int j=0;j<8;j++){ s += v[j]*as_s[c0+j]; d += v[j]*ad_s[c0+j]; }
      #pragma unroll
      for (int off=1; off<16; off<<=1){ s += __shfl_xor(s,off); d += __shfl_xor(d,off); }
      if ((t & 15)==0 && r < M){ asrc[r]=s; adst[r]=d; }
    }
  }
}

// ---------------- GAT aggregation: wave per node (R9 x2 body) ----------------
__global__ __launch_bounds__(256) void k_agg(const int* __restrict__ rowptr, const uint4* __restrict__ csr,
    const float* __restrict__ asrc, const float* __restrict__ adst,
    const unsigned short* __restrict__ xlbf,
    const float* __restrict__ bias, float* __restrict__ out, int relu, int layer){
  int w = threadIdx.x >> 6;
  int lane = threadIdx.x & 63;
  int n = blockIdx.x * WPB + w;          // grid exact
  __shared__ float2 eb[WPB][MAXDEG];     // {alpha->weight, byteoff bits}
  const char* xbase = (const char*)xlbf; // row = 256 B
  int s0 = rowptr[n], s1 = rowptr[n+1];
  int deg = s1 - s0;
  float adst_n = adst[n];
  // pass A
  float m_edge = -1e30f;
  float sae = 0.f;
  for (int base=0; base<deg; base+=64){
    int i = base + lane;
    float a = -1e30f;
    if (i < deg){
      uint4 p4 = csr[s0 + i];
      int sx = (int)p4.x;
      float ae = __uint_as_float(layer ? p4.z : p4.y);
      float av = lrelu(asrc[sx] + adst_n + ae);
      if (i < MAXDEG) eb[w][i] = make_float2(av, __uint_as_float((unsigned)sx << 8));
      a = av;
      sae += ae;
    }
    for (int off=32; off; off>>=1) a = fmaxf(a, __shfl_xor(a, off));
    m_edge = fmaxf(m_edge, a);
  }
  for (int off=32; off; off>>=1) sae += __shfl_xor(sae, off);
  float aloop_n = sae / fmaxf((float)deg, 1.f);
  float al = lrelu(asrc[n] + adst_n + aloop_n);   // self-loop alpha
  float m = fmaxf(m_edge, al);
  // pass B
  float p = 0.f;
  for (int i=lane; i<deg; i+=64){
    float av;
    if (i < MAXDEG) av = eb[w][i].x;
    else { uint4 p4 = csr[s0+i];
           av = lrelu(asrc[p4.x] + adst_n + __uint_as_float(layer ? p4.z : p4.y)); }
    float ev = __expf(av - m);
    if (i < MAXDEG) eb[w][i].x = ev;
    p += ev;
  }
  for (int off=32; off; off>>=1) p += __shfl_xor(p, off);
  float wl = __expf(al - m);
  float denom = p + wl;
  __syncthreads();
  // pass C
  int g = lane >> 4, cl = lane & 15;
  unsigned clb = (unsigned)(cl << 4);
  float acc[8];
  #pragma unroll
  for (int j=0;j<8;j++) acc[j]=0.f;
  if (g == 0){
    uint4 v = *(const uint4*)(xbase + (((unsigned)n << 8) + clb));
    unsigned int uu[4] = {v.x,v.y,v.z,v.w};
    #pragma unroll
    for (int q=0;q<4;q++){
      acc[2*q]   += wl * __uint_as_float(uu[q] << 16);
      acc[2*q+1] += wl * __uint_as_float(uu[q] & 0xFFFF0000u);
    }
  }
  if (deg <= MAXDEG){
    int dfull = deg & ~7;
    for (int i=0; i<dfull; i+=8){      // unguarded main body
      float2 e0 = eb[w][i+g];
      float2 e1 = eb[w][i+4+g];
      uint4 v0 = *(const uint4*)(xbase + (__float_as_uint(e0.y) + clb));
      uint4 v1 = *(const uint4*)(xbase + (__float_as_uint(e1.y) + clb));
      unsigned int uu0[4] = {v0.x,v0.y,v0.z,v0.w};
      unsigned int uu1[4] = {v1.x,v1.y,v1.z,v1.w};
      #pragma unroll
      for (int q=0;q<4;q++){
        acc[2*q]   += e0.x * __uint_as_float(uu0[q] << 16);
        acc[2*q+1] += e0.x * __uint_as_float(uu0[q] & 0xFFFF0000u);
      }
      #pragma unroll
      for (int q=0;q<4;q++){
        acc[2*q]   += e1.x * __uint_as_float(uu1[q] << 16);
        acc[2*q+1] += e1.x * __uint_as_float(uu1[q] & 0xFFFF0000u);
      }
    }
    for (int i=dfull; i<deg; i+=4){    // guarded tail (<8 edges)
      int idx = i + g;
      float we = 0.f; unsigned off = (unsigned)n << 8;
      if (idx < deg){ float2 e = eb[w][idx]; we = e.x; off = __float_as_uint(e.y); }
      uint4 v = *(const uint4*)(xbase + (off + clb));
      unsigned int uu[4] = {v.x,v.y,v.z,v.w};
      #pragma unroll
      for (int q=0;q<4;q++){
        acc[2*q]   += we * __uint_as_float(uu[q] << 16);
        acc[2*q+1] += we * __uint_as_float(uu[q] & 0xFFFF0000u);
      }
    }
  } else {
    for (int i=0; i<deg; i+=8){
      int idx0 = i + g, idx1 = i + 4 + g;
      int sx0 = n, sx1 = n; float we0 = 0.f, we1 = 0.f;
      if (idx0 < deg){
        if (idx0 < MAXDEG){ float2 e = eb[w][idx0]; we0 = e.x; sx0 = (int)(__float_as_uint(e.y) >> 8); }
        else { uint4 p4 = csr[s0+idx0]; sx0 = (int)p4.x;
               we0 = __expf(lrelu(asrc[sx0] + adst_n + __uint_as_float(layer ? p4.z : p4.y)) - m); }
      }
      if (idx1 < deg){
        if (idx1 < MAXDEG){ float2 e = eb[w][idx1]; we1 = e.x; sx1 = (int)(__float_as_uint(e.y) >> 8); }
        else { uint4 p4 = csr[s0+idx1]; sx1 = (int)p4.x;
               we1 = __expf(lrelu(asrc[sx1] + adst_n + __uint_as_float(layer ? p4.z : p4.y)) - m); }
      }
      uint4 v0 = *(const uint4*)(xbase + (((unsigned)sx0 << 8) + clb));
      uint4 v1 = *(const uint4*)(xbase + (((unsigned)sx1 << 8) + clb));
      unsigned int uu0[4] = {v0.x,v0.y,v0.z,v0.w};
      unsigned int uu1[4] = {v1.x,v1.y,v1.z,v1.w};
      #pragma unroll
      for (int q=0;q<4;q++){
        acc[2*q]   += we0 * __uint_as_float(uu0[q] << 16);
        acc[2*q+1] += we0 * __uint_as_float(uu0[q] & 0xFFFF0000u);
      }
      #pragma unroll
      for (int q=0;q<4;q++){
        acc[2*q]   += we1 * __uint_as_float(uu1[q] << 16);
        acc[2*q+1] += we1 * __uint_as_float(uu1[q] & 0xFFFF0000u);
      }
    }
  }
  #pragma unroll
  for (int j=0;j<8;j++){
    acc[j] += __shfl_xor(acc[j], 16);
    acc[j] += __shfl_xor(acc[j], 32);
  }
  if (lane < 16){
    float inv = 1.f/denom;
    float4 b0 = *(const float4*)(bias + cl*8);
    float4 b1 = *(const float4*)(bias + cl*8 + 4);
    float o[8];
    o[0]=acc[0]*inv+b0.x; o[1]=acc[1]*inv+b0.y; o[2]=acc[2]*inv+b0.z; o[3]=acc[3]*inv+b0.w;
    o[4]=acc[4]*inv+b1.x; o[5]=acc[5]*inv+b1.y; o[6]=acc[6]*inv+b1.z; o[7]=acc[7]*inv+b1.w;
    if (relu){
      #pragma unroll
      for (int j=0;j<8;j++) o[j]=fmaxf(o[j],0.f);
    }
    *(float4*)(out + (size_t)n*128 + cl*8)     = make_float4(o[0],o[1],o[2],o[3]);
    *(float4*)(out + (size_t)n*128 + cl*8 + 4) = make_float4(o[4],o[5],o[6],o[7]);
  }
}

// ---------------- fused MLP: lin1 GEMM -> lin2 -> log_softmax ----------------
__global__ __launch_bounds__(256) void k_mlp(const float* __restrict__ X, const float* __restrict__ W,
    const float* __restrict__ bias, const float* __restrict__ w2, const float* __restrict__ b2,
    float* __restrict__ out, int M){
  __shared__ float Xs[16][68];
  __shared__ float Ws[16][128];
  __shared__ float b2s[16];
  int t = threadIdx.x;
  int row0 = blockIdx.x * 64;
  int tc = t & 15, tr = t >> 4;
  int c0 = tc*8, r0 = tr*4;
  int lr = t >> 2, lc = (t & 3) << 2;
  int wk = t >> 4, wc = (t & 15) * 8;
  float acc[4][8];
  #pragma unroll
  for (int i=0;i<4;i++)
    #pragma unroll
    for (int j=0;j<8;j++) acc[i][j]=0.f;
  int gr = row0 + lr;
  for (int k0=0; k0<128; k0+=16){
    float4 xv = make_float4(0.f,0.f,0.f,0.f);
    if (gr < M) xv = *(const float4*)(X + (size_t)gr*128 + k0 + lc);
    float4 wv0 = *(const float4*)(W + (size_t)(k0+wk)*128 + wc);
    float4 wv1 = *(const float4*)(W + (size_t)(k0+wk)*128 + wc + 4);
    __syncthreads();
    Xs[lc+0][lr]=xv.x; Xs[lc+1][lr]=xv.y; Xs[lc+2][lr]=xv.z; Xs[lc+3][lr]=xv.w;
    *(float4*)&Ws[wk][wc]   = wv0;
    *(float4*)&Ws[wk][wc+4] = wv1;
    __syncthreads();
    #pragma unroll
    for (int kk=0;kk<16;kk++){
      float4 a  = *(const float4*)&Xs[kk][r0];
      float4 b0 = *(const float4*)&Ws[kk][c0];
      float4 b1 = *(const float4*)&Ws[kk][c0+4];
      float av[4] = {a.x,a.y,a.z,a.w};
      float bv[8] = {b0.x,b0.y,b0.z,b0.w,b1.x,b1.y,b1.z,b1.w};
      #pragma unroll
      for (int i=0;i<4;i++)
        #pragma unroll
        for (int j=0;j<8;j++) acc[i][j] += av[i]*bv[j];
    }
  }
  __syncthreads();   // all Ws reads done before restage
  float* wflat = &Ws[0][0];   // w2 restaged here: wflat[col*16 + cls]
  #pragma unroll
  for (int i=0;i<2;i++) ((float4*)wflat)[t + i*256] = ((const float4*)w2)[t + i*256];
  if (t < 16) b2s[t] = b2[t];
  // h = relu(acc + l1b) in registers
  float4 bba = *(const float4*)(bias + c0);
  float4 bbb = *(const float4*)(bias + c0 + 4);
  float bb[8] = {bba.x,bba.y,bba.z,bba.w,bbb.x,bbb.y,bbb.z,bbb.w};
  #pragma unroll
  for (int i=0;i<4;i++)
    #pragma unroll
    for (int j=0;j<8;j++) acc[i][j] = fmaxf(acc[i][j] + bb[j], 0.f);
  __syncthreads();   // w2/b2 staged
  // ring-rotate lin2: conflict-free w2 reads (banks j*16+cls, cls distinct)
  float A0=0.f, A1=0.f, A2=0.f, A3=0.f;
  int sl = (tc+1) & 15;
  #pragma unroll 4
  for (int s=0; s<16; s++){
    int cls = (tc + s) & 15;
    const float* wp = wflat + (size_t)c0*16 + cls;
    float p0=0.f,p1=0.f,p2=0.f,p3=0.f;
    #pragma unroll
    for (int j=0;j<8;j++){
      float wv = wp[j*16];
      p0 += acc[0][j]*wv; p1 += acc[1][j]*wv; p2 += acc[2][j]*wv; p3 += acc[3][j]*wv;
    }
    A0+=p0; A1+=p1; A2+=p2; A3+=p3;
    A0=__shfl(A0,sl,16); A1=__shfl(A1,sl,16); A2=__shfl(A2,sl,16); A3=__shfl(A3,sl,16);
  }
  float A[4] = {A0,A1,A2,A3};
  float bcls = b2s[tc];
  #pragma unroll
  for (int i=0;i<4;i++){
    float v = A[i] + bcls;
    float m = v;
    #pragma unroll
    for (int off=1; off<16; off<<=1) m = fmaxf(m, __shfl_xor(m, off, 16));
    float ex = __expf(v - m);
    float sum = ex;
    #pragma unroll
    for (int off=1; off<16; off<<=1) sum += __shfl_xor(sum, off, 16);
    float lse = m + __logf(sum);
    int r = row0 + r0 + i;
    if (r < M) out[(size_t)r*16 + tc] = v - lse;
  }
}

extern "C" void kernel_launch(void* const* d_in, const int* in_sizes, int n_in,
                              void* d_out, int out_size, void* d_ws, size_t ws_size,
                              hipStream_t stream){
  const float* x    = (const float*)d_in[0];
  const float* eatt = (const float*)d_in[1];
  const float* W0   = (const float*)d_in[2];
  const float* as0  = (const float*)d_in[3];
  const float* ad0  = (const float*)d_in[4];
  const float* We0  = (const float*)d_in[5];
  const float* ae0  = (const float*)d_in[6];
  const float* b0   = (const float*)d_in[7];
  const float* W1   = (const float*)d_in[8];
  const float* as1  = (const float*)d_in[9];
  const float* ad1  = (const float*)d_in[10];
  const float* We1  = (const float*)d_in[11];
  const float* ae1  = (const float*)d_in[12];
  const float* b1   = (const float*)d_in[13];
  const float* l1w  = (const float*)d_in[14];
  const float* l1b  = (const float*)d_in[15];
  const float* l2w  = (const float*)d_in[16];
  const float* l2b  = (const float*)d_in[17];
  const int*   ei   = (const int*)d_in[18];
  const int* srcI = ei;
  const int* dstI = ei + N_EDGES;
  float* out = (float*)d_out;

  char* p = (char*)d_ws;
  auto alloc = [&](size_t bytes)->char*{ char* r = p; p += (bytes + 255) & ~255ull; return r; };
  unsigned short* Abf = (unsigned short*)alloc((size_t)N_NODES*128*2); // bf16 features
  float* B       = (float*)alloc((size_t)N_NODES*128*4);   // aggregation output
  float* asrc    = (float*)alloc((size_t)N_NODES*4);
  float* adst    = (float*)alloc((size_t)N_NODES*4);
  int* deg     = (int*)alloc((size_t)N_NODES*4);
  int* rowptr  = (int*)alloc((size_t)(N_NODES+1)*4);
  uint4* csr   = (uint4*)alloc((size_t)N_EDGES*16);
  int* incl    = (int*)alloc((size_t)N_NODES*4);
  int* bsum    = (int*)alloc(512*4);
  int* bexcl   = (int*)alloc(512*4);
  // k_pre's GEMM role writes Abf concurrently with the deg role, so
  // rank/ae01 both live in the B region (dead until agg0 writes B, after
  // fillf has consumed them).
  char*   Bc   = (char*)B;
  int*    rank = (int*)Bc;                    // 6.4MB
  float2* ae01 = (float2*)(Bc + 6400000);     // 12.8MB, ends at 19.2MB < 51.2MB

  const int NB_E = (N_EDGES+255)/256;   // 6250
  const int NB_N = (N_NODES+255)/256;   // 391
  const int NB_W = N_NODES/WPB;         // 25000 (exact)
  const int NB_G = (N_NODES+63)/64;     // 1563
  const int NB_P = 6250;                // 3125 deg-role (512 e) + 3125 gemm-role (32 rows)

  // ---- fused preprocessing + layer-0 GEMM ----
  hipMemsetAsync(deg, 0, (size_t)N_NODES*4, stream);
  k_pre  <<<NB_P,256,0,stream>>>(dstI, eatt, We0, ae0, We1, ae1, deg, rank, ae01,
                                 x, W0, as0, ad0, Abf, asrc, adst);
  k_scan_a<<<NB_N,256,0,stream>>>(deg, incl, bsum);
  k_scan_b<<<1,  512,0,stream>>>(bsum, bexcl, NB_N);
  k_scan_c<<<NB_N,256,0,stream>>>(incl, deg, bexcl, rowptr);
  k_fillf <<<NB_E,256,0,stream>>>(srcI, dstI, rank, ae01, rowptr, csr);

  // ---- layer 0 aggregation (GEMM already done in k_pre) ----
  k_agg  <<<NB_W,256,0,stream>>>(rowptr, csr, asrc, adst, Abf, b0, B, 1, 0);

  // ---- layer 1 ----
  k_gemm <<<NB_G,256,0,stream>>>(B, W1, nullptr, nullptr, Abf, as1, ad1, asrc, adst, N_NODES, 0);
  k_agg  <<<NB_W,256,0,stream>>>(rowptr, csr, asrc, adst, Abf, b1, B, 1, 1);

  // ---- post MLP (lin1 + lin2 + log_softmax fused) ----
  k_mlp  <<<NB_G,256,0,stream>>>(B, l1w, l1b, l2w, l2b, out, N_NODES);
}

// Round 8
// 634.424 us; speedup vs baseline: 1.0161x; 1.0161x over previous
//
#include <hip/hip_runtime.h>
#include <math.h>

#define N_NODES 100000
#define N_EDGES 1600000
#define NEG 0.2f
#define MAXDEG 128
#define WPB 4     // waves per block for per-node kernels
#define NBK 391   // dst>>8 buckets (256 nodes each; bucket 390 has 160)
#define CHK 6250  // edges per count/part block (256 blocks * 6250 = 1.6M exact)

__device__ __forceinline__ float lrelu(float x){ return x > 0.f ? x : NEG*x; }
__device__ __forceinline__ unsigned short f2bf(float f){
  unsigned int u = __float_as_uint(f);
  u += 0x7FFFu + ((u >> 16) & 1u);   // RNE
  return (unsigned short)(u >> 16);
}

// ============ R14: sort-based CSR build ============
// R10-R13 established: 1.6M random device atomics run at a fixed memory-side
// rate (~84us) regardless of scope/privatization/co-resident work, and the
// random 16B csr scatter costs ~70us in 64B line allocations (101MB WRITE).
// Replace both with a 2-level bucket sort: LDS histograms cut global atomics
// 16x, and per-bucket CSR writes land in 65KB windows that L2 write-combines.

// ---- count: per-block LDS histogram over dst>>8 ----
__global__ __launch_bounds__(512) void k_count(const int* __restrict__ dst, int* __restrict__ gcount){
  __shared__ unsigned hist[NBK];
  int t = threadIdx.x;
  for (int b=t; b<NBK; b+=512) hist[b]=0;
  __syncthreads();
  int base = blockIdx.x * CHK;
  for (int i=t; i<CHK; i+=512){
    int d = dst[base+i];
    atomicAdd(&hist[d>>8], 1u);
  }
  __syncthreads();
  for (int b=t; b<NBK; b+=512){
    unsigned h = hist[b];
    if (h) atomicAdd(&gcount[b], (int)h);
  }
}

// ---- bucket scan + cursor init + wea dots + rowptr sentinel ----
__global__ __launch_bounds__(512) void k_bscan(const int* __restrict__ gcount,
    int* __restrict__ gbase, int* __restrict__ gcursor,
    const float* __restrict__ We0, const float* __restrict__ ae0,
    const float* __restrict__ We1, const float* __restrict__ ae1,
    float* __restrict__ wea01, int* __restrict__ rowptr){
  __shared__ int s[512];
  int t = threadIdx.x;
  int v = (t<NBK)? gcount[t] : 0;
  s[t]=v; __syncthreads();
  for (int off=1; off<512; off<<=1){
    int u = (t>=off)? s[t-off]:0; __syncthreads();
    s[t]+=u; __syncthreads();
  }
  if (t<NBK){ int e = s[t]-v; gbase[t]=e; gcursor[t]=e; }
  if (t==NBK) gbase[NBK]=N_EDGES;
  if (t==0) rowptr[N_NODES]=N_EDGES;
  if (t<32){
    const float* W = (t<16)? We0 : We1;
    const float* a = (t<16)? ae0 : ae1;
    int r = t & 15;
    float acc = 0.f;
    #pragma unroll
    for (int j=0;j<128;j++) acc += W[r*128+j]*a[j];
    wea01[t]=acc;
  }
}

// ---- partition: scatter packed (eid | dlow<<21) into bucket regions ----
__global__ __launch_bounds__(512) void k_part(const int* __restrict__ dst,
    int* __restrict__ gcursor, unsigned* __restrict__ part){
  __shared__ unsigned hist[NBK];
  __shared__ int bbase[NBK];
  __shared__ unsigned cur[NBK];
  int t = threadIdx.x;
  for (int b=t; b<NBK; b+=512) hist[b]=0;
  __syncthreads();
  int base = blockIdx.x * CHK;
  for (int i=t; i<CHK; i+=512) atomicAdd(&hist[dst[base+i]>>8], 1u);
  __syncthreads();
  for (int b=t; b<NBK; b+=512){
    unsigned h = hist[b];
    bbase[b] = h ? atomicAdd(&gcursor[b], (int)h) : 0;
    cur[b]=0;
  }
  __syncthreads();
  for (int i=t; i<CHK; i+=512){
    int e = base+i;
    int d = dst[e];
    int bin = d>>8;
    unsigned off = atomicAdd(&cur[bin], 1u);
    part[bbase[bin]+(int)off] = (unsigned)e | ((unsigned)(d&255)<<21);  // eid<2^21
  }
}

// ---- build: per-bucket rowptr + csr (edge-att dots computed here) ----
__global__ __launch_bounds__(512) void k_build(const int* __restrict__ gbase,
    const unsigned* __restrict__ part, const int* __restrict__ src,
    const float* __restrict__ eatt, const float* __restrict__ wea01,
    int* __restrict__ rowptr, uint4* __restrict__ csr){
  __shared__ unsigned cnt[256];
  __shared__ int rb[256];
  __shared__ unsigned s[256];
  __shared__ float wea[32];
  int t = threadIdx.x;
  int b = blockIdx.x;
  int lo = gbase[b], hi = gbase[b+1];
  if (t<32) wea[t]=wea01[t];
  if (t<256) cnt[t]=0;
  __syncthreads();
  for (int i=lo+t; i<hi; i+=512) atomicAdd(&cnt[part[i]>>21], 1u);
  __syncthreads();
  if (t<256) s[t]=cnt[t];
  __syncthreads();
  for (int off=1; off<256; off<<=1){
    unsigned u = 0;
    if (t<256 && t>=off) u = s[t-off];
    __syncthreads();
    if (t<256) s[t]+=u;
    __syncthreads();
  }
  if (t<256){
    int bn = lo + (int)(s[t]-cnt[t]);
    rb[t]=bn;
    int node = (b<<8)+t;
    if (node < N_NODES) rowptr[node]=bn;
    cnt[t]=0;
  }
  __syncthreads();
  for (int i=lo+t; i<hi; i+=512){
    unsigned p = part[i];
    int eid = (int)(p & 0x1FFFFFu);
    int dl  = (int)(p >> 21);
    const float4* pe = (const float4*)(eatt + (size_t)eid*16);
    float4 a0=pe[0], a1=pe[1], a2=pe[2], a3=pe[3];
    // identical association order to the R6 dot -> bit-exact per edge
    float f0 = a0.x*wea[0] +a0.y*wea[1] +a0.z*wea[2] +a0.w*wea[3]
             + a1.x*wea[4] +a1.y*wea[5] +a1.z*wea[6] +a1.w*wea[7]
             + a2.x*wea[8] +a2.y*wea[9] +a2.z*wea[10]+a2.w*wea[11]
             + a3.x*wea[12]+a3.y*wea[13]+a3.z*wea[14]+a3.w*wea[15];
    float f1 = a0.x*wea[16]+a0.y*wea[17]+a0.z*wea[18]+a0.w*wea[19]
             + a1.x*wea[20]+a1.y*wea[21]+a1.z*wea[22]+a1.w*wea[23]
             + a2.x*wea[24]+a2.y*wea[25]+a2.z*wea[26]+a2.w*wea[27]
             + a3.x*wea[28]+a3.y*wea[29]+a3.z*wea[30]+a3.w*wea[31];
    int sx = src[eid];
    unsigned off = atomicAdd(&cnt[dl], 1u);
    csr[rb[dl]+(int)off] = make_uint4((unsigned)sx, __float_as_uint(f0), __float_as_uint(f1), 0u);
  }
}

// ---------------- fp32 GEMM + optional fused attention dots ----------------
__global__ __launch_bounds__(256) void k_gemm(const float* __restrict__ X, const float* __restrict__ W,
    const float* __restrict__ bias, float* __restrict__ Y, unsigned short* __restrict__ Ybf,
    const float* __restrict__ a_s, const float* __restrict__ a_d,
    float* __restrict__ asrc, float* __restrict__ adst, int M, int relu){
  __shared__ float Xs[16][68];
  __shared__ float Ws[16][128];
  __shared__ float as_s[128], ad_s[128];
  int t = threadIdx.x;
  if (a_s && t < 128){ as_s[t] = a_s[t]; ad_s[t] = a_d[t]; }
  int row0 = blockIdx.x * 64;
  int tc = t & 15, tr = t >> 4;
  int c0 = tc*8, r0 = tr*4;
  int lr = t >> 2, lc = (t & 3) << 2;
  int wk = t >> 4, wc = (t & 15) * 8;
  float acc[4][8];
  #pragma unroll
  for (int i=0;i<4;i++)
    #pragma unroll
    for (int j=0;j<8;j++) acc[i][j]=0.f;
  int gr = row0 + lr;
  for (int k0=0; k0<128; k0+=16){
    float4 xv = make_float4(0.f,0.f,0.f,0.f);
    if (gr < M) xv = *(const float4*)(X + (size_t)gr*128 + k0 + lc);
    float4 wv0 = *(const float4*)(W + (size_t)(k0+wk)*128 + wc);
    float4 wv1 = *(const float4*)(W + (size_t)(k0+wk)*128 + wc + 4);
    __syncthreads();
    Xs[lc+0][lr]=xv.x; Xs[lc+1][lr]=xv.y; Xs[lc+2][lr]=xv.z; Xs[lc+3][lr]=xv.w;
    *(float4*)&Ws[wk][wc]   = wv0;
    *(float4*)&Ws[wk][wc+4] = wv1;
    __syncthreads();
    #pragma unroll
    for (int kk=0;kk<16;kk++){
      float4 a  = *(const float4*)&Xs[kk][r0];
      float4 b0 = *(const float4*)&Ws[kk][c0];
      float4 b1 = *(const float4*)&Ws[kk][c0+4];
      float av[4] = {a.x,a.y,a.z,a.w};
      float bv[8] = {b0.x,b0.y,b0.z,b0.w,b1.x,b1.y,b1.z,b1.w};
      #pragma unroll
      for (int i=0;i<4;i++)
        #pragma unroll
        for (int j=0;j<8;j++) acc[i][j] += av[i]*bv[j];
    }
  }
  #pragma unroll
  for (int i=0;i<4;i++){
    int r = row0 + r0 + i;
    float v[8];
    #pragma unroll
    for (int j=0;j<8;j++){
      float u = acc[i][j] + (bias ? bias[c0+j] : 0.f);
      v[j] = relu ? fmaxf(u, 0.f) : u;
    }
    if (r < M){
      if (Y){
        *(float4*)(Y + (size_t)r*128 + c0)     = make_float4(v[0],v[1],v[2],v[3]);
        *(float4*)(Y + (size_t)r*128 + c0 + 4) = make_float4(v[4],v[5],v[6],v[7]);
      }
      if (Ybf){
        uint4 pk;
        pk.x = (unsigned)f2bf(v[0]) | ((unsigned)f2bf(v[1])<<16);
        pk.y = (unsigned)f2bf(v[2]) | ((unsigned)f2bf(v[3])<<16);
        pk.z = (unsigned)f2bf(v[4]) | ((unsigned)f2bf(v[5])<<16);
        pk.w = (unsigned)f2bf(v[6]) | ((unsigned)f2bf(v[7])<<16);
        *(uint4*)(Ybf + (size_t)r*128 + c0) = pk;
      }
    }
    if (a_s){
      float s=0.f, d=0.f;
      #pragma unroll
      for (int j=0;j<8;j++){ s += v[j]*as_s[c0+j]; d += v[j]*ad_s[c0+j]; }
      #pragma unroll
      for (int off=1; off<16; off<<=1){ s += __shfl_xor(s,off); d += __shfl_xor(d,off); }
      if ((t & 15)==0 && r < M){ asrc[r]=s; adst[r]=d; }
    }
  }
}

// ---------------- GAT aggregation: wave per node (R9/R12 x2 body) ----------------
__global__ __launch_bounds__(256) void k_agg(const int* __restrict__ rowptr, const uint4* __restrict__ csr,
    const float* __restrict__ asrc, const float* __restrict__ adst,
    const unsigned short* __restrict__ xlbf,
    const float* __restrict__ bias, float* __restrict__ out, int relu, int layer){
  int w = threadIdx.x >> 6;
  int lane = threadIdx.x & 63;
  int n = blockIdx.x * WPB + w;          // grid exact
  __shared__ float2 eb[WPB][MAXDEG];     // {alpha->weight, byteoff bits}
  const char* xbase = (const char*)xlbf; // row = 256 B
  int s0 = rowptr[n], s1 = rowptr[n+1];
  int deg = s1 - s0;
  float adst_n = adst[n];
  // pass A
  float m_edge = -1e30f;
  float sae = 0.f;
  for (int base=0; base<deg; base+=64){
    int i = base + lane;
    float a = -1e30f;
    if (i < deg){
      uint4 p4 = csr[s0 + i];
      int sx = (int)p4.x;
      float ae = __uint_as_float(layer ? p4.z : p4.y);
      float av = lrelu(asrc[sx] + adst_n + ae);
      if (i < MAXDEG) eb[w][i] = make_float2(av, __uint_as_float((unsigned)sx << 8));
      a = av;
      sae += ae;
    }
    for (int off=32; off; off>>=1) a = fmaxf(a, __shfl_xor(a, off));
    m_edge = fmaxf(m_edge, a);
  }
  for (int off=32; off; off>>=1) sae += __shfl_xor(sae, off);
  float aloop_n = sae / fmaxf((float)deg, 1.f);
  float al = lrelu(asrc[n] + adst_n + aloop_n);   // self-loop alpha
  float m = fmaxf(m_edge, al);
  // pass B
  float p = 0.f;
  for (int i=lane; i<deg; i+=64){
    float av;
    if (i < MAXDEG) av = eb[w][i].x;
    else { uint4 p4 = csr[s0+i];
           av = lrelu(asrc[p4.x] + adst_n + __uint_as_float(layer ? p4.z : p4.y)); }
    float ev = __expf(av - m);
    if (i < MAXDEG) eb[w][i].x = ev;
    p += ev;
  }
  for (int off=32; off; off>>=1) p += __shfl_xor(p, off);
  float wl = __expf(al - m);
  float denom = p + wl;
  __syncthreads();
  // pass C
  int g = lane >> 4, cl = lane & 15;
  unsigned clb = (unsigned)(cl << 4);
  float acc[8];
  #pragma unroll
  for (int j=0;j<8;j++) acc[j]=0.f;
  if (g == 0){
    uint4 v = *(const uint4*)(xbase + (((unsigned)n << 8) + clb));
    unsigned int uu[4] = {v.x,v.y,v.z,v.w};
    #pragma unroll
    for (int q=0;q<4;q++){
      acc[2*q]   += wl * __uint_as_float(uu[q] << 16);
      acc[2*q+1] += wl * __uint_as_float(uu[q] & 0xFFFF0000u);
    }
  }
  if (deg <= MAXDEG){
    int dfull = deg & ~7;
    for (int i=0; i<dfull; i+=8){      // unguarded main body
      float2 e0 = eb[w][i+g];
      float2 e1 = eb[w][i+4+g];
      uint4 v0 = *(const uint4*)(xbase + (__float_as_uint(e0.y) + clb));
      uint4 v1 = *(const uint4*)(xbase + (__float_as_uint(e1.y) + clb));
      unsigned int uu0[4] = {v0.x,v0.y,v0.z,v0.w};
      unsigned int uu1[4] = {v1.x,v1.y,v1.z,v1.w};
      #pragma unroll
      for (int q=0;q<4;q++){
        acc[2*q]   += e0.x * __uint_as_float(uu0[q] << 16);
        acc[2*q+1] += e0.x * __uint_as_float(uu0[q] & 0xFFFF0000u);
      }
      #pragma unroll
      for (int q=0;q<4;q++){
        acc[2*q]   += e1.x * __uint_as_float(uu1[q] << 16);
        acc[2*q+1] += e1.x * __uint_as_float(uu1[q] & 0xFFFF0000u);
      }
    }
    for (int i=dfull; i<deg; i+=4){    // guarded tail (<8 edges)
      int idx = i + g;
      float we = 0.f; unsigned off = (unsigned)n << 8;
      if (idx < deg){ float2 e = eb[w][idx]; we = e.x; off = __float_as_uint(e.y); }
      uint4 v = *(const uint4*)(xbase + (off + clb));
      unsigned int uu[4] = {v.x,v.y,v.z,v.w};
      #pragma unroll
      for (int q=0;q<4;q++){
        acc[2*q]   += we * __uint_as_float(uu[q] << 16);
        acc[2*q+1] += we * __uint_as_float(uu[q] & 0xFFFF0000u);
      }
    }
  } else {
    for (int i=0; i<deg; i+=8){
      int idx0 = i + g, idx1 = i + 4 + g;
      int sx0 = n, sx1 = n; float we0 = 0.f, we1 = 0.f;
      if (idx0 < deg){
        if (idx0 < MAXDEG){ float2 e = eb[w][idx0]; we0 = e.x; sx0 = (int)(__float_as_uint(e.y) >> 8); }
        else { uint4 p4 = csr[s0+idx0]; sx0 = (int)p4.x;
               we0 = __expf(lrelu(asrc[sx0] + adst_n + __uint_as_float(layer ? p4.z : p4.y)) - m); }
      }
      if (idx1 < deg){
        if (idx1 < MAXDEG){ float2 e = eb[w][idx1]; we1 = e.x; sx1 = (int)(__float_as_uint(e.y) >> 8); }
        else { uint4 p4 = csr[s0+idx1]; sx1 = (int)p4.x;
               we1 = __expf(lrelu(asrc[sx1] + adst_n + __uint_as_float(layer ? p4.z : p4.y)) - m); }
      }
      uint4 v0 = *(const uint4*)(xbase + (((unsigned)sx0 << 8) + clb));
      uint4 v1 = *(const uint4*)(xbase + (((unsigned)sx1 << 8) + clb));
      unsigned int uu0[4] = {v0.x,v0.y,v0.z,v0.w};
      unsigned int uu1[4] = {v1.x,v1.y,v1.z,v1.w};
      #pragma unroll
      for (int q=0;q<4;q++){
        acc[2*q]   += we0 * __uint_as_float(uu0[q] << 16);
        acc[2*q+1] += we0 * __uint_as_float(uu0[q] & 0xFFFF0000u);
      }
      #pragma unroll
      for (int q=0;q<4;q++){
        acc[2*q]   += we1 * __uint_as_float(uu1[q] << 16);
        acc[2*q+1] += we1 * __uint_as_float(uu1[q] & 0xFFFF0000u);
      }
    }
  }
  #pragma unroll
  for (int j=0;j<8;j++){
    acc[j] += __shfl_xor(acc[j], 16);
    acc[j] += __shfl_xor(acc[j], 32);
  }
  if (lane < 16){
    float inv = 1.f/denom;
    float4 b0 = *(const float4*)(bias + cl*8);
    float4 b1 = *(const float4*)(bias + cl*8 + 4);
    float o[8];
    o[0]=acc[0]*inv+b0.x; o[1]=acc[1]*inv+b0.y; o[2]=acc[2]*inv+b0.z; o[3]=acc[3]*inv+b0.w;
    o[4]=acc[4]*inv+b1.x; o[5]=acc[5]*inv+b1.y; o[6]=acc[6]*inv+b1.z; o[7]=acc[7]*inv+b1.w;
    if (relu){
      #pragma unroll
      for (int j=0;j<8;j++) o[j]=fmaxf(o[j],0.f);
    }
    *(float4*)(out + (size_t)n*128 + cl*8)     = make_float4(o[0],o[1],o[2],o[3]);
    *(float4*)(out + (size_t)n*128 + cl*8 + 4) = make_float4(o[4],o[5],o[6],o[7]);
  }
}

// ---------------- fused MLP: lin1 GEMM -> lin2 -> log_softmax ----------------
__global__ __launch_bounds__(256) void k_mlp(const float* __restrict__ X, const float* __restrict__ W,
    const float* __restrict__ bias, const float* __restrict__ w2, const float* __restrict__ b2,
    float* __restrict__ out, int M){
  __shared__ float Xs[16][68];
  __shared__ float Ws[16][128];
  __shared__ float b2s[16];
  int t = threadIdx.x;
  int row0 = blockIdx.x * 64;
  int tc = t & 15, tr = t >> 4;
  int c0 = tc*8, r0 = tr*4;
  int lr = t >> 2, lc = (t & 3) << 2;
  int wk = t >> 4, wc = (t & 15) * 8;
  float acc[4][8];
  #pragma unroll
  for (int i=0;i<4;i++)
    #pragma unroll
    for (int j=0;j<8;j++) acc[i][j]=0.f;
  int gr = row0 + lr;
  for (int k0=0; k0<128; k0+=16){
    float4 xv = make_float4(0.f,0.f,0.f,0.f);
    if (gr < M) xv = *(const float4*)(X + (size_t)gr*128 + k0 + lc);
    float4 wv0 = *(const float4*)(W + (size_t)(k0+wk)*128 + wc);
    float4 wv1 = *(const float4*)(W + (size_t)(k0+wk)*128 + wc + 4);
    __syncthreads();
    Xs[lc+0][lr]=xv.x; Xs[lc+1][lr]=xv.y; Xs[lc+2][lr]=xv.z; Xs[lc+3][lr]=xv.w;
    *(float4*)&Ws[wk][wc]   = wv0;
    *(float4*)&Ws[wk][wc+4] = wv1;
    __syncthreads();
    #pragma unroll
    for (int kk=0;kk<16;kk++){
      float4 a  = *(const float4*)&Xs[kk][r0];
      float4 b0 = *(const float4*)&Ws[kk][c0];
      float4 b1 = *(const float4*)&Ws[kk][c0+4];
      float av[4] = {a.x,a.y,a.z,a.w};
      float bv[8] = {b0.x,b0.y,b0.z,b0.w,b1.x,b1.y,b1.z,b1.w};
      #pragma unroll
      for (int i=0;i<4;i++)
        #pragma unroll
        for (int j=0;j<8;j++) acc[i][j] += av[i]*bv[j];
    }
  }
  __syncthreads();   // all Ws reads done before restage
  float* wflat = &Ws[0][0];   // w2 restaged here: wflat[col*16 + cls]
  #pragma unroll
  for (int i=0;i<2;i++) ((float4*)wflat)[t + i*256] = ((const float4*)w2)[t + i*256];
  if (t < 16) b2s[t] = b2[t];
  // h = relu(acc + l1b) in registers
  float4 bba = *(const float4*)(bias + c0);
  float4 bbb = *(const float4*)(bias + c0 + 4);
  float bb[8] = {bba.x,bba.y,bba.z,bba.w,bbb.x,bbb.y,bbb.z,bbb.w};
  #pragma unroll
  for (int i=0;i<4;i++)
    #pragma unroll
    for (int j=0;j<8;j++) acc[i][j] = fmaxf(acc[i][j] + bb[j], 0.f);
  __syncthreads();   // w2/b2 staged
  // ring-rotate lin2: conflict-free w2 reads (banks j*16+cls, cls distinct)
  float A0=0.f, A1=0.f, A2=0.f, A3=0.f;
  int sl = (tc+1) & 15;
  #pragma unroll 4
  for (int s=0; s<16; s++){
    int cls = (tc + s) & 15;
    const float* wp = wflat + (size_t)c0*16 + cls;
    float p0=0.f,p1=0.f,p2=0.f,p3=0.f;
    #pragma unroll
    for (int j=0;j<8;j++){
      float wv = wp[j*16];
      p0 += acc[0][j]*wv; p1 += acc[1][j]*wv; p2 += acc[2][j]*wv; p3 += acc[3][j]*wv;
    }
    A0+=p0; A1+=p1; A2+=p2; A3+=p3;
    A0=__shfl(A0,sl,16); A1=__shfl(A1,sl,16); A2=__shfl(A2,sl,16); A3=__shfl(A3,sl,16);
  }
  float A[4] = {A0,A1,A2,A3};
  float bcls = b2s[tc];
  #pragma unroll
  for (int i=0;i<4;i++){
    float v = A[i] + bcls;
    float m = v;
    #pragma unroll
    for (int off=1; off<16; off<<=1) m = fmaxf(m, __shfl_xor(m, off, 16));
    float ex = __expf(v - m);
    float sum = ex;
    #pragma unroll
    for (int off=1; off<16; off<<=1) sum += __shfl_xor(sum, off, 16);
    float lse = m + __logf(sum);
    int r = row0 + r0 + i;
    if (r < M) out[(size_t)r*16 + tc] = v - lse;
  }
}

extern "C" void kernel_launch(void* const* d_in, const int* in_sizes, int n_in,
                              void* d_out, int out_size, void* d_ws, size_t ws_size,
                              hipStream_t stream){
  const float* x    = (const float*)d_in[0];
  const float* eatt = (const float*)d_in[1];
  const float* W0   = (const float*)d_in[2];
  const float* as0  = (const float*)d_in[3];
  const float* ad0  = (const float*)d_in[4];
  const float* We0  = (const float*)d_in[5];
  const float* ae0  = (const float*)d_in[6];
  const float* b0   = (const float*)d_in[7];
  const float* W1   = (const float*)d_in[8];
  const float* as1  = (const float*)d_in[9];
  const float* ad1  = (const float*)d_in[10];
  const float* We1  = (const float*)d_in[11];
  const float* ae1  = (const float*)d_in[12];
  const float* b1   = (const float*)d_in[13];
  const float* l1w  = (const float*)d_in[14];
  const float* l1b  = (const float*)d_in[15];
  const float* l2w  = (const float*)d_in[16];
  const float* l2b  = (const float*)d_in[17];
  const int*   ei   = (const int*)d_in[18];
  const int* srcI = ei;
  const int* dstI = ei + N_EDGES;
  float* out = (float*)d_out;

  char* p = (char*)d_ws;
  auto alloc = [&](size_t bytes)->char*{ char* r = p; p += (bytes + 255) & ~255ull; return r; };
  unsigned short* Abf = (unsigned short*)alloc((size_t)N_NODES*128*2); // bf16 features
  float* B       = (float*)alloc((size_t)N_NODES*128*4);   // aggregation output
  float* asrc    = (float*)alloc((size_t)N_NODES*4);
  float* adst    = (float*)alloc((size_t)N_NODES*4);
  int* rowptr  = (int*)alloc((size_t)(N_NODES+1)*4);
  uint4* csr   = (uint4*)alloc((size_t)N_EDGES*16);
  int* gcount  = (int*)alloc(400*4);
  int* gbase   = (int*)alloc(400*4);
  int* gcursor = (int*)alloc(400*4);
  float* wea01 = (float*)alloc(128);
  // part (6.4MB) lives in the B region: written by k_part, read by k_build,
  // both strictly before agg0 overwrites B.
  unsigned* part = (unsigned*)B;

  const int NB_W = N_NODES/WPB;         // 25000 (exact)
  const int NB_G = (N_NODES+63)/64;     // 1563

  // ---- preprocessing: 2-level bucket sort -> rowptr + csr ----
  hipMemsetAsync(gcount, 0, 400*4, stream);
  k_count<<<256,512,0,stream>>>(dstI, gcount);
  k_bscan<<<1,  512,0,stream>>>(gcount, gbase, gcursor, We0, ae0, We1, ae1, wea01, rowptr);
  k_part <<<256,512,0,stream>>>(dstI, gcursor, part);
  // layer-0 GEMM (independent of preprocessing)
  k_gemm <<<NB_G,256,0,stream>>>(x, W0, nullptr, nullptr, Abf, as0, ad0, asrc, adst, N_NODES, 0);
  k_build<<<NBK,512,0,stream>>>(gbase, part, srcI, eatt, wea01, rowptr, csr);

  // ---- layer 0 aggregation ----
  k_agg  <<<NB_W,256,0,stream>>>(rowptr, csr, asrc, adst, Abf, b0, B, 1, 0);

  // ---- layer 1 ----
  k_gemm <<<NB_G,256,0,stream>>>(B, W1, nullptr, nullptr, Abf, as1, ad1, asrc, adst, N_NODES, 0);
  k_agg  <<<NB_W,256,0,stream>>>(rowptr, csr, asrc, adst, Abf, b1, B, 1, 1);

  // ---- post MLP (lin1 + lin2 + log_softmax fused) ----
  k_mlp  <<<NB_G,256,0,stream>>>(B, l1w, l1b, l2w, l2b, out, N_NODES);
}

// Round 9
// 611.585 us; speedup vs baseline: 1.0540x; 1.0373x over previous
//
#include <hip/hip_runtime.h>
#include <math.h>

#define N_NODES 100000
#define N_EDGES 1600000
#define NEG 0.2f
#define MAXDEG 128
#define WPB 4     // waves per block for per-node kernels
#define NBK 391   // dst>>8 buckets (256 nodes each; bucket 390 has 160)
#define CHK 6250  // edges per count/part block (256 blocks * 6250 = 1.6M exact)

__device__ __forceinline__ float lrelu(float x){ return x > 0.f ? x : NEG*x; }
__device__ __forceinline__ unsigned short f2bf(float f){
  unsigned int u = __float_as_uint(f);
  u += 0x7FFFu + ((u >> 16) & 1u);   // RNE
  return (unsigned short)(u >> 16);
}

// ============ R15: sort-based CSR build, fill stage fixed ============
// R14: write-combining confirmed (WRITE 101->49MB) but k_build was 113.8us
// at 1.6% VALU / 27.9% occupancy: 391-block grid + serial random 64B eatt
// gathers (102MB uncacheable). R15: (a) dots precomputed via COALESCED eatt
// stream in k_count -> k_fill gathers 8B ae01 from a 12.8MB L2/L3-resident
// set; (b) fill split per bucket-quarter (1564 blocks) with qpre base table.

// ---- count: per-block LDS histogram over dst>>8 + coalesced ae01 dots ----
__global__ __launch_bounds__(512) void k_count(const int* __restrict__ dst, const float* __restrict__ eatt,
    const float* __restrict__ We0, const float* __restrict__ ae0,
    const float* __restrict__ We1, const float* __restrict__ ae1,
    int* __restrict__ gcount, float2* __restrict__ ae01){
  __shared__ unsigned hist[NBK];
  __shared__ float wea[32];
  int t = threadIdx.x;
  if (t < 32){
    const float* W = (t < 16) ? We0 : We1;
    const float* a = (t < 16) ? ae0 : ae1;
    int r = t & 15;
    float acc = 0.f;
    #pragma unroll
    for (int j=0;j<128;j++) acc += W[r*128+j]*a[j];
    wea[t] = acc;
  }
  for (int b=t; b<NBK; b+=512) hist[b]=0;
  __syncthreads();
  int base = blockIdx.x * CHK;
  for (int i=t; i<CHK; i+=512){
    int e = base+i;
    int d = dst[e];
    atomicAdd(&hist[d>>8], 1u);
    const float4* p = (const float4*)(eatt + (size_t)e*16);
    float4 a0=p[0], a1=p[1], a2=p[2], a3=p[3];
    // identical association order to the R6 dot -> bit-exact per edge
    float f0 = a0.x*wea[0] +a0.y*wea[1] +a0.z*wea[2] +a0.w*wea[3]
             + a1.x*wea[4] +a1.y*wea[5] +a1.z*wea[6] +a1.w*wea[7]
             + a2.x*wea[8] +a2.y*wea[9] +a2.z*wea[10]+a2.w*wea[11]
             + a3.x*wea[12]+a3.y*wea[13]+a3.z*wea[14]+a3.w*wea[15];
    float f1 = a0.x*wea[16]+a0.y*wea[17]+a0.z*wea[18]+a0.w*wea[19]
             + a1.x*wea[20]+a1.y*wea[21]+a1.z*wea[22]+a1.w*wea[23]
             + a2.x*wea[24]+a2.y*wea[25]+a2.z*wea[26]+a2.w*wea[27]
             + a3.x*wea[28]+a3.y*wea[29]+a3.z*wea[30]+a3.w*wea[31];
    ae01[e] = make_float2(f0, f1);
  }
  __syncthreads();
  for (int b=t; b<NBK; b+=512){
    unsigned h = hist[b];
    if (h) atomicAdd(&gcount[b], (int)h);
  }
}

// ---- bucket scan + cursor init + rowptr sentinel ----
__global__ __launch_bounds__(512) void k_bscan(const int* __restrict__ gcount,
    int* __restrict__ gbase, int* __restrict__ gcursor, int* __restrict__ rowptr){
  __shared__ int s[512];
  int t = threadIdx.x;
  int v = (t<NBK)? gcount[t] : 0;
  s[t]=v; __syncthreads();
  for (int off=1; off<512; off<<=1){
    int u = (t>=off)? s[t-off]:0; __syncthreads();
    s[t]+=u; __syncthreads();
  }
  if (t<NBK){ int e = s[t]-v; gbase[t]=e; gcursor[t]=e; }
  if (t==NBK) gbase[NBK]=N_EDGES;
  if (t==0) rowptr[N_NODES]=N_EDGES;
}

// ---- partition: scatter packed (eid | dlow<<21) into bucket regions ----
__global__ __launch_bounds__(512) void k_part(const int* __restrict__ dst,
    int* __restrict__ gcursor, unsigned* __restrict__ part){
  __shared__ unsigned hist[NBK];
  __shared__ int bbase[NBK];
  __shared__ unsigned cur[NBK];
  int t = threadIdx.x;
  for (int b=t; b<NBK; b+=512) hist[b]=0;
  __syncthreads();
  int base = blockIdx.x * CHK;
  for (int i=t; i<CHK; i+=512) atomicAdd(&hist[dst[base+i]>>8], 1u);
  __syncthreads();
  for (int b=t; b<NBK; b+=512){
    unsigned h = hist[b];
    bbase[b] = h ? atomicAdd(&gcursor[b], (int)h) : 0;
    cur[b]=0;
  }
  __syncthreads();
  for (int i=t; i<CHK; i+=512){
    int e = base+i;
    int d = dst[e];
    int bin = d>>8;
    unsigned off = atomicAdd(&cur[bin], 1u);
    part[bbase[bin]+(int)off] = (unsigned)e | ((unsigned)(d&255)<<21);  // eid<2^21
  }
}

// ---- build_a: per-bucket per-quarter histograms -> rowptr + qpre bases ----
__global__ __launch_bounds__(512) void k_build_a(const int* __restrict__ gbase,
    const unsigned* __restrict__ part, int* __restrict__ rowptr, int* __restrict__ qpre){
  __shared__ unsigned cntq[4][256];
  __shared__ unsigned s[256];
  int t = threadIdx.x;
  int b = blockIdx.x;
  int lo = gbase[b], hi = gbase[b+1];
  int len = hi - lo;
  int q1 = lo + ((len*1)>>2), q2 = lo + ((len*2)>>2), q3 = lo + ((len*3)>>2);
  for (int k=t; k<1024; k+=512) ((unsigned*)cntq)[k] = 0u;
  __syncthreads();
  for (int i=lo+t; i<hi; i+=512){
    unsigned p = part[i];
    int node = (int)(p >> 21);
    int q = (i>=q1) + (i>=q2) + (i>=q3);
    atomicAdd(&cntq[q][node], 1u);
  }
  __syncthreads();
  unsigned tot = 0;
  if (t<256){ tot = cntq[0][t]+cntq[1][t]+cntq[2][t]+cntq[3][t]; s[t]=tot; }
  __syncthreads();
  for (int off=1; off<256; off<<=1){
    unsigned u = 0;
    if (t<256 && t>=off) u = s[t-off];
    __syncthreads();
    if (t<256) s[t]+=u;
    __syncthreads();
  }
  if (t<256){
    int rb = lo + (int)(s[t]-tot);
    int node = (b<<8)+t;
    if (node < N_NODES) rowptr[node]=rb;
    int run = rb;
    #pragma unroll
    for (int q=0;q<4;q++){
      qpre[((b*4+q)<<8) + t] = run;
      run += (int)cntq[q][t];
    }
  }
}

// ---- fill: one bucket-quarter per block; gather 8B ae01 + 4B src ----
__global__ __launch_bounds__(256) void k_fill(const int* __restrict__ gbase,
    const unsigned* __restrict__ part, const int* __restrict__ src,
    const float2* __restrict__ ae01, const int* __restrict__ qpre,
    uint4* __restrict__ csr){
  __shared__ unsigned cur[256];
  int t = threadIdx.x;
  int bq = blockIdx.x;
  int b = bq >> 2, q = bq & 3;
  int lo = gbase[b], hi = gbase[b+1];
  int len = hi - lo;
  int ql = lo + ((len*q)>>2);
  int qh = lo + ((len*(q+1))>>2);
  cur[t] = (unsigned)qpre[(bq<<8) + t];
  __syncthreads();
  for (int i = ql + t; i < qh; i += 512){
    int i1 = i + 256;
    bool has1 = i1 < qh;
    unsigned p0 = part[i];
    unsigned p1 = has1 ? part[i1] : p0;
    int e0 = (int)(p0 & 0x1FFFFFu), n0 = (int)(p0 >> 21);
    int e1 = (int)(p1 & 0x1FFFFFu), n1 = (int)(p1 >> 21);
    float2 ae_a = ae01[e0];
    float2 ae_b = ae01[e1];
    int s0 = src[e0], s1 = src[e1];
    unsigned o0 = atomicAdd(&cur[n0], 1u);
    csr[o0] = make_uint4((unsigned)s0, __float_as_uint(ae_a.x), __float_as_uint(ae_a.y), 0u);
    if (has1){
      unsigned o1 = atomicAdd(&cur[n1], 1u);
      csr[o1] = make_uint4((unsigned)s1, __float_as_uint(ae_b.x), __float_as_uint(ae_b.y), 0u);
    }
  }
}

// ---------------- fp32 GEMM + optional fused attention dots ----------------
__global__ __launch_bounds__(256) void k_gemm(const float* __restrict__ X, const float* __restrict__ W,
    const float* __restrict__ bias, float* __restrict__ Y, unsigned short* __restrict__ Ybf,
    const float* __restrict__ a_s, const float* __restrict__ a_d,
    float* __restrict__ asrc, float* __restrict__ adst, int M, int relu){
  __shared__ float Xs[16][68];
  __shared__ float Ws[16][128];
  __shared__ float as_s[128], ad_s[128];
  int t = threadIdx.x;
  if (a_s && t < 128){ as_s[t] = a_s[t]; ad_s[t] = a_d[t]; }
  int row0 = blockIdx.x * 64;
  int tc = t & 15, tr = t >> 4;
  int c0 = tc*8, r0 = tr*4;
  int lr = t >> 2, lc = (t & 3) << 2;
  int wk = t >> 4, wc = (t & 15) * 8;
  float acc[4][8];
  #pragma unroll
  for (int i=0;i<4;i++)
    #pragma unroll
    for (int j=0;j<8;j++) acc[i][j]=0.f;
  int gr = row0 + lr;
  for (int k0=0; k0<128; k0+=16){
    float4 xv = make_float4(0.f,0.f,0.f,0.f);
    if (gr < M) xv = *(const float4*)(X + (size_t)gr*128 + k0 + lc);
    float4 wv0 = *(const float4*)(W + (size_t)(k0+wk)*128 + wc);
    float4 wv1 = *(const float4*)(W + (size_t)(k0+wk)*128 + wc + 4);
    __syncthreads();
    Xs[lc+0][lr]=xv.x; Xs[lc+1][lr]=xv.y; Xs[lc+2][lr]=xv.z; Xs[lc+3][lr]=xv.w;
    *(float4*)&Ws[wk][wc]   = wv0;
    *(float4*)&Ws[wk][wc+4] = wv1;
    __syncthreads();
    #pragma unroll
    for (int kk=0;kk<16;kk++){
      float4 a  = *(const float4*)&Xs[kk][r0];
      float4 b0 = *(const float4*)&Ws[kk][c0];
      float4 b1 = *(const float4*)&Ws[kk][c0+4];
      float av[4] = {a.x,a.y,a.z,a.w};
      float bv[8] = {b0.x,b0.y,b0.z,b0.w,b1.x,b1.y,b1.z,b1.w};
      #pragma unroll
      for (int i=0;i<4;i++)
        #pragma unroll
        for (int j=0;j<8;j++) acc[i][j] += av[i]*bv[j];
    }
  }
  #pragma unroll
  for (int i=0;i<4;i++){
    int r = row0 + r0 + i;
    float v[8];
    #pragma unroll
    for (int j=0;j<8;j++){
      float u = acc[i][j] + (bias ? bias[c0+j] : 0.f);
      v[j] = relu ? fmaxf(u, 0.f) : u;
    }
    if (r < M){
      if (Y){
        *(float4*)(Y + (size_t)r*128 + c0)     = make_float4(v[0],v[1],v[2],v[3]);
        *(float4*)(Y + (size_t)r*128 + c0 + 4) = make_float4(v[4],v[5],v[6],v[7]);
      }
      if (Ybf){
        uint4 pk;
        pk.x = (unsigned)f2bf(v[0]) | ((unsigned)f2bf(v[1])<<16);
        pk.y = (unsigned)f2bf(v[2]) | ((unsigned)f2bf(v[3])<<16);
        pk.z = (unsigned)f2bf(v[4]) | ((unsigned)f2bf(v[5])<<16);
        pk.w = (unsigned)f2bf(v[6]) | ((unsigned)f2bf(v[7])<<16);
        *(uint4*)(Ybf + (size_t)r*128 + c0) = pk;
      }
    }
    if (a_s){
      float s=0.f, d=0.f;
      #pragma unroll
      for (int j=0;j<8;j++){ s += v[j]*as_s[c0+j]; d += v[j]*ad_s[c0+j]; }
      #pragma unroll
      for (int off=1; off<16; off<<=1){ s += __shfl_xor(s,off); d += __shfl_xor(d,off); }
      if ((t & 15)==0 && r < M){ asrc[r]=s; adst[r]=d; }
    }
  }
}

// ---------------- GAT aggregation: wave per node (R9/R12 x2 body) ----------------
__global__ __launch_bounds__(256) void k_agg(const int* __restrict__ rowptr, const uint4* __restrict__ csr,
    const float* __restrict__ asrc, const float* __restrict__ adst,
    const unsigned short* __restrict__ xlbf,
    const float* __restrict__ bias, float* __restrict__ out, int relu, int layer){
  int w = threadIdx.x >> 6;
  int lane = threadIdx.x & 63;
  int n = blockIdx.x * WPB + w;          // grid exact
  __shared__ float2 eb[WPB][MAXDEG];     // {alpha->weight, byteoff bits}
  const char* xbase = (const char*)xlbf; // row = 256 B
  int s0 = rowptr[n], s1 = rowptr[n+1];
  int deg = s1 - s0;
  float adst_n = adst[n];
  // pass A
  float m_edge = -1e30f;
  float sae = 0.f;
  for (int base=0; base<deg; base+=64){
    int i = base + lane;
    float a = -1e30f;
    if (i < deg){
      uint4 p4 = csr[s0 + i];
      int sx = (int)p4.x;
      float ae = __uint_as_float(layer ? p4.z : p4.y);
      float av = lrelu(asrc[sx] + adst_n + ae);
      if (i < MAXDEG) eb[w][i] = make_float2(av, __uint_as_float((unsigned)sx << 8));
      a = av;
      sae += ae;
    }
    for (int off=32; off; off>>=1) a = fmaxf(a, __shfl_xor(a, off));
    m_edge = fmaxf(m_edge, a);
  }
  for (int off=32; off; off>>=1) sae += __shfl_xor(sae, off);
  float aloop_n = sae / fmaxf((float)deg, 1.f);
  float al = lrelu(asrc[n] + adst_n + aloop_n);   // self-loop alpha
  float m = fmaxf(m_edge, al);
  // pass B
  float p = 0.f;
  for (int i=lane; i<deg; i+=64){
    float av;
    if (i < MAXDEG) av = eb[w][i].x;
    else { uint4 p4 = csr[s0+i];
           av = lrelu(asrc[p4.x] + adst_n + __uint_as_float(layer ? p4.z : p4.y)); }
    float ev = __expf(av - m);
    if (i < MAXDEG) eb[w][i].x = ev;
    p += ev;
  }
  for (int off=32; off; off>>=1) p += __shfl_xor(p, off);
  float wl = __expf(al - m);
  float denom = p + wl;
  __syncthreads();
  // pass C
  int g = lane >> 4, cl = lane & 15;
  unsigned clb = (unsigned)(cl << 4);
  float acc[8];
  #pragma unroll
  for (int j=0;j<8;j++) acc[j]=0.f;
  if (g == 0){
    uint4 v = *(const uint4*)(xbase + (((unsigned)n << 8) + clb));
    unsigned int uu[4] = {v.x,v.y,v.z,v.w};
    #pragma unroll
    for (int q=0;q<4;q++){
      acc[2*q]   += wl * __uint_as_float(uu[q] << 16);
      acc[2*q+1] += wl * __uint_as_float(uu[q] & 0xFFFF0000u);
    }
  }
  if (deg <= MAXDEG){
    int dfull = deg & ~7;
    for (int i=0; i<dfull; i+=8){      // unguarded main body
      float2 e0 = eb[w][i+g];
      float2 e1 = eb[w][i+4+g];
      uint4 v0 = *(const uint4*)(xbase + (__float_as_uint(e0.y) + clb));
      uint4 v1 = *(const uint4*)(xbase + (__float_as_uint(e1.y) + clb));
      unsigned int uu0[4] = {v0.x,v0.y,v0.z,v0.w};
      unsigned int uu1[4] = {v1.x,v1.y,v1.z,v1.w};
      #pragma unroll
      for (int q=0;q<4;q++){
        acc[2*q]   += e0.x * __uint_as_float(uu0[q] << 16);
        acc[2*q+1] += e0.x * __uint_as_float(uu0[q] & 0xFFFF0000u);
      }
      #pragma unroll
      for (int q=0;q<4;q++){
        acc[2*q]   += e1.x * __uint_as_float(uu1[q] << 16);
        acc[2*q+1] += e1.x * __uint_as_float(uu1[q] & 0xFFFF0000u);
      }
    }
    for (int i=dfull; i<deg; i+=4){    // guarded tail (<8 edges)
      int idx = i + g;
      float we = 0.f; unsigned off = (unsigned)n << 8;
      if (idx < deg){ float2 e = eb[w][idx]; we = e.x; off = __float_as_uint(e.y); }
      uint4 v = *(const uint4*)(xbase + (off + clb));
      unsigned int uu[4] = {v.x,v.y,v.z,v.w};
      #pragma unroll
      for (int q=0;q<4;q++){
        acc[2*q]   += we * __uint_as_float(uu[q] << 16);
        acc[2*q+1] += we * __uint_as_float(uu[q] & 0xFFFF0000u);
      }
    }
  } else {
    for (int i=0; i<deg; i+=8){
      int idx0 = i + g, idx1 = i + 4 + g;
      int sx0 = n, sx1 = n; float we0 = 0.f, we1 = 0.f;
      if (idx0 < deg){
        if (idx0 < MAXDEG){ float2 e = eb[w][idx0]; we0 = e.x; sx0 = (int)(__float_as_uint(e.y) >> 8); }
        else { uint4 p4 = csr[s0+idx0]; sx0 = (int)p4.x;
               we0 = __expf(lrelu(asrc[sx0] + adst_n + __uint_as_float(layer ? p4.z : p4.y)) - m); }
      }
      if (idx1 < deg){
        if (idx1 < MAXDEG){ float2 e = eb[w][idx1]; we1 = e.x; sx1 = (int)(__float_as_uint(e.y) >> 8); }
        else { uint4 p4 = csr[s0+idx1]; sx1 = (int)p4.x;
               we1 = __expf(lrelu(asrc[sx1] + adst_n + __uint_as_float(layer ? p4.z : p4.y)) - m); }
      }
      uint4 v0 = *(const uint4*)(xbase + (((unsigned)sx0 << 8) + clb));
      uint4 v1 = *(const uint4*)(xbase + (((unsigned)sx1 << 8) + clb));
      unsigned int uu0[4] = {v0.x,v0.y,v0.z,v0.w};
      unsigned int uu1[4] = {v1.x,v1.y,v1.z,v1.w};
      #pragma unroll
      for (int q=0;q<4;q++){
        acc[2*q]   += we0 * __uint_as_float(uu0[q] << 16);
        acc[2*q+1] += we0 * __uint_as_float(uu0[q] & 0xFFFF0000u);
      }
      #pragma unroll
      for (int q=0;q<4;q++){
        acc[2*q]   += we1 * __uint_as_float(uu1[q] << 16);
        acc[2*q+1] += we1 * __uint_as_float(uu1[q] & 0xFFFF0000u);
      }
    }
  }
  #pragma unroll
  for (int j=0;j<8;j++){
    acc[j] += __shfl_xor(acc[j], 16);
    acc[j] += __shfl_xor(acc[j], 32);
  }
  if (lane < 16){
    float inv = 1.f/denom;
    float4 b0 = *(const float4*)(bias + cl*8);
    float4 b1 = *(const float4*)(bias + cl*8 + 4);
    float o[8];
    o[0]=acc[0]*inv+b0.x; o[1]=acc[1]*inv+b0.y; o[2]=acc[2]*inv+b0.z; o[3]=acc[3]*inv+b0.w;
    o[4]=acc[4]*inv+b1.x; o[5]=acc[5]*inv+b1.y; o[6]=acc[6]*inv+b1.z; o[7]=acc[7]*inv+b1.w;
    if (relu){
      #pragma unroll
      for (int j=0;j<8;j++) o[j]=fmaxf(o[j],0.f);
    }
    *(float4*)(out + (size_t)n*128 + cl*8)     = make_float4(o[0],o[1],o[2],o[3]);
    *(float4*)(out + (size_t)n*128 + cl*8 + 4) = make_float4(o[4],o[5],o[6],o[7]);
  }
}

// ---------------- fused MLP: lin1 GEMM -> lin2 -> log_softmax ----------------
__global__ __launch_bounds__(256) void k_mlp(const float* __restrict__ X, const float* __restrict__ W,
    const float* __restrict__ bias, const float* __restrict__ w2, const float* __restrict__ b2,
    float* __restrict__ out, int M){
  __shared__ float Xs[16][68];
  __shared__ float Ws[16][128];
  __shared__ float b2s[16];
  int t = threadIdx.x;
  int row0 = blockIdx.x * 64;
  int tc = t & 15, tr = t >> 4;
  int c0 = tc*8, r0 = tr*4;
  int lr = t >> 2, lc = (t & 3) << 2;
  int wk = t >> 4, wc = (t & 15) * 8;
  float acc[4][8];
  #pragma unroll
  for (int i=0;i<4;i++)
    #pragma unroll
    for (int j=0;j<8;j++) acc[i][j]=0.f;
  int gr = row0 + lr;
  for (int k0=0; k0<128; k0+=16){
    float4 xv = make_float4(0.f,0.f,0.f,0.f);
    if (gr < M) xv = *(const float4*)(X + (size_t)gr*128 + k0 + lc);
    float4 wv0 = *(const float4*)(W + (size_t)(k0+wk)*128 + wc);
    float4 wv1 = *(const float4*)(W + (size_t)(k0+wk)*128 + wc + 4);
    __syncthreads();
    Xs[lc+0][lr]=xv.x; Xs[lc+1][lr]=xv.y; Xs[lc+2][lr]=xv.z; Xs[lc+3][lr]=xv.w;
    *(float4*)&Ws[wk][wc]   = wv0;
    *(float4*)&Ws[wk][wc+4] = wv1;
    __syncthreads();
    #pragma unroll
    for (int kk=0;kk<16;kk++){
      float4 a  = *(const float4*)&Xs[kk][r0];
      float4 b0 = *(const float4*)&Ws[kk][c0];
      float4 b1 = *(const float4*)&Ws[kk][c0+4];
      float av[4] = {a.x,a.y,a.z,a.w};
      float bv[8] = {b0.x,b0.y,b0.z,b0.w,b1.x,b1.y,b1.z,b1.w};
      #pragma unroll
      for (int i=0;i<4;i++)
        #pragma unroll
        for (int j=0;j<8;j++) acc[i][j] += av[i]*bv[j];
    }
  }
  __syncthreads();   // all Ws reads done before restage
  float* wflat = &Ws[0][0];   // w2 restaged here: wflat[col*16 + cls]
  #pragma unroll
  for (int i=0;i<2;i++) ((float4*)wflat)[t + i*256] = ((const float4*)w2)[t + i*256];
  if (t < 16) b2s[t] = b2[t];
  // h = relu(acc + l1b) in registers
  float4 bba = *(const float4*)(bias + c0);
  float4 bbb = *(const float4*)(bias + c0 + 4);
  float bb[8] = {bba.x,bba.y,bba.z,bba.w,bbb.x,bbb.y,bbb.z,bbb.w};
  #pragma unroll
  for (int i=0;i<4;i++)
    #pragma unroll
    for (int j=0;j<8;j++) acc[i][j] = fmaxf(acc[i][j] + bb[j], 0.f);
  __syncthreads();   // w2/b2 staged
  // ring-rotate lin2: conflict-free w2 reads (banks j*16+cls, cls distinct)
  float A0=0.f, A1=0.f, A2=0.f, A3=0.f;
  int sl = (tc+1) & 15;
  #pragma unroll 4
  for (int s=0; s<16; s++){
    int cls = (tc + s) & 15;
    const float* wp = wflat + (size_t)c0*16 + cls;
    float p0=0.f,p1=0.f,p2=0.f,p3=0.f;
    #pragma unroll
    for (int j=0;j<8;j++){
      float wv = wp[j*16];
      p0 += acc[0][j]*wv; p1 += acc[1][j]*wv; p2 += acc[2][j]*wv; p3 += acc[3][j]*wv;
    }
    A0+=p0; A1+=p1; A2+=p2; A3+=p3;
    A0=__shfl(A0,sl,16); A1=__shfl(A1,sl,16); A2=__shfl(A2,sl,16); A3=__shfl(A3,sl,16);
  }
  float A[4] = {A0,A1,A2,A3};
  float bcls = b2s[tc];
  #pragma unroll
  for (int i=0;i<4;i++){
    float v = A[i] + bcls;
    float m = v;
    #pragma unroll
    for (int off=1; off<16; off<<=1) m = fmaxf(m, __shfl_xor(m, off, 16));
    float ex = __expf(v - m);
    float sum = ex;
    #pragma unroll
    for (int off=1; off<16; off<<=1) sum += __shfl_xor(sum, off, 16);
    float lse = m + __logf(sum);
    int r = row0 + r0 + i;
    if (r < M) out[(size_t)r*16 + tc] = v - lse;
  }
}

extern "C" void kernel_launch(void* const* d_in, const int* in_sizes, int n_in,
                              void* d_out, int out_size, void* d_ws, size_t ws_size,
                              hipStream_t stream){
  const float* x    = (const float*)d_in[0];
  const float* eatt = (const float*)d_in[1];
  const float* W0   = (const float*)d_in[2];
  const float* as0  = (const float*)d_in[3];
  const float* ad0  = (const float*)d_in[4];
  const float* We0  = (const float*)d_in[5];
  const float* ae0  = (const float*)d_in[6];
  const float* b0   = (const float*)d_in[7];
  const float* W1   = (const float*)d_in[8];
  const float* as1  = (const float*)d_in[9];
  const float* ad1  = (const float*)d_in[10];
  const float* We1  = (const float*)d_in[11];
  const float* ae1  = (const float*)d_in[12];
  const float* b1   = (const float*)d_in[13];
  const float* l1w  = (const float*)d_in[14];
  const float* l1b  = (const float*)d_in[15];
  const float* l2w  = (const float*)d_in[16];
  const float* l2b  = (const float*)d_in[17];
  const int*   ei   = (const int*)d_in[18];
  const int* srcI = ei;
  const int* dstI = ei + N_EDGES;
  float* out = (float*)d_out;

  char* p = (char*)d_ws;
  auto alloc = [&](size_t bytes)->char*{ char* r = p; p += (bytes + 255) & ~255ull; return r; };
  unsigned short* Abf = (unsigned short*)alloc((size_t)N_NODES*128*2); // bf16 features
  float* B       = (float*)alloc((size_t)N_NODES*128*4);   // aggregation output
  float* asrc    = (float*)alloc((size_t)N_NODES*4);
  float* adst    = (float*)alloc((size_t)N_NODES*4);
  int* rowptr  = (int*)alloc((size_t)(N_NODES+1)*4);
  uint4* csr   = (uint4*)alloc((size_t)N_EDGES*16);
  int* gcount  = (int*)alloc(400*4);
  int* gbase   = (int*)alloc(400*4);
  int* gcursor = (int*)alloc(400*4);
  // part (6.4MB), qpre (1.6MB), ae01 (12.8MB) live in the B region: all
  // written and consumed strictly before agg0 overwrites B.
  char* Bc = (char*)B;
  unsigned* part = (unsigned*)Bc;                    // 6.4MB
  int*      qpre = (int*)(Bc + 6400000);             // 1.6MB (391*4*256*4)
  float2*   ae01 = (float2*)(Bc + 6400000 + 1602560);// 12.8MB, ends ~20.8MB < 51.2MB

  const int NB_W = N_NODES/WPB;         // 25000 (exact)
  const int NB_G = (N_NODES+63)/64;     // 1563

  // ---- preprocessing: 2-level bucket sort -> rowptr + csr ----
  hipMemsetAsync(gcount, 0, 400*4, stream);
  k_count<<<256,512,0,stream>>>(dstI, eatt, We0, ae0, We1, ae1, gcount, ae01);
  k_bscan<<<1,  512,0,stream>>>(gcount, gbase, gcursor, rowptr);
  k_part <<<256,512,0,stream>>>(dstI, gcursor, part);
  k_build_a<<<NBK,512,0,stream>>>(gbase, part, rowptr, qpre);
  // layer-0 GEMM (independent of preprocessing)
  k_gemm <<<NB_G,256,0,stream>>>(x, W0, nullptr, nullptr, Abf, as0, ad0, asrc, adst, N_NODES, 0);
  k_fill <<<NBK*4,256,0,stream>>>(gbase, part, srcI, ae01, qpre, csr);

  // ---- layer 0 aggregation ----
  k_agg  <<<NB_W,256,0,stream>>>(rowptr, csr, asrc, adst, Abf, b0, B, 1, 0);

  // ---- layer 1 ----
  k_gemm <<<NB_G,256,0,stream>>>(B, W1, nullptr, nullptr, Abf, as1, ad1, asrc, adst, N_NODES, 0);
  k_agg  <<<NB_W,256,0,stream>>>(rowptr, csr, asrc, adst, Abf, b1, B, 1, 1);

  // ---- post MLP (lin1 + lin2 + log_softmax fused) ----
  k_mlp  <<<NB_G,256,0,stream>>>(B, l1w, l1b, l2w, l2b, out, N_NODES);
}

// Round 10
// 606.975 us; speedup vs baseline: 1.0620x; 1.0076x over previous
//
#include <hip/hip_runtime.h>
#include <math.h>

#define N_NODES 100000
#define N_EDGES 1600000
#define NEG 0.2f
#define MAXDEG 128
#define WPB 4     // waves per block for per-node kernels
#define NBK 391   // dst>>8 buckets (256 nodes each; bucket 390 has 160)
#define CHK 6250  // edges per count/part block (256 blocks * 6250 = 1.6M exact)

__device__ __forceinline__ float lrelu(float x){ return x > 0.f ? x : NEG*x; }
__device__ __forceinline__ unsigned short f2bf(float f){
  unsigned int u = __float_as_uint(f);
  u += 0x7FFFu + ((u >> 16) & 1u);   // RNE
  return (unsigned short)(u >> 16);
}

// ============ R15: sort-based CSR build (verified: k_build 113.8us -> gone) ============

// ---- count: per-block LDS histogram over dst>>8 + coalesced ae01 dots ----
__global__ __launch_bounds__(512) void k_count(const int* __restrict__ dst, const float* __restrict__ eatt,
    const float* __restrict__ We0, const float* __restrict__ ae0,
    const float* __restrict__ We1, const float* __restrict__ ae1,
    int* __restrict__ gcount, float2* __restrict__ ae01){
  __shared__ unsigned hist[NBK];
  __shared__ float wea[32];
  int t = threadIdx.x;
  if (t < 32){
    const float* W = (t < 16) ? We0 : We1;
    const float* a = (t < 16) ? ae0 : ae1;
    int r = t & 15;
    float acc = 0.f;
    #pragma unroll
    for (int j=0;j<128;j++) acc += W[r*128+j]*a[j];
    wea[t] = acc;
  }
  for (int b=t; b<NBK; b+=512) hist[b]=0;
  __syncthreads();
  int base = blockIdx.x * CHK;
  for (int i=t; i<CHK; i+=512){
    int e = base+i;
    int d = dst[e];
    atomicAdd(&hist[d>>8], 1u);
    const float4* p = (const float4*)(eatt + (size_t)e*16);
    float4 a0=p[0], a1=p[1], a2=p[2], a3=p[3];
    // identical association order to the R6 dot -> bit-exact per edge
    float f0 = a0.x*wea[0] +a0.y*wea[1] +a0.z*wea[2] +a0.w*wea[3]
             + a1.x*wea[4] +a1.y*wea[5] +a1.z*wea[6] +a1.w*wea[7]
             + a2.x*wea[8] +a2.y*wea[9] +a2.z*wea[10]+a2.w*wea[11]
             + a3.x*wea[12]+a3.y*wea[13]+a3.z*wea[14]+a3.w*wea[15];
    float f1 = a0.x*wea[16]+a0.y*wea[17]+a0.z*wea[18]+a0.w*wea[19]
             + a1.x*wea[20]+a1.y*wea[21]+a1.z*wea[22]+a1.w*wea[23]
             + a2.x*wea[24]+a2.y*wea[25]+a2.z*wea[26]+a2.w*wea[27]
             + a3.x*wea[28]+a3.y*wea[29]+a3.z*wea[30]+a3.w*wea[31];
    ae01[e] = make_float2(f0, f1);
  }
  __syncthreads();
  for (int b=t; b<NBK; b+=512){
    unsigned h = hist[b];
    if (h) atomicAdd(&gcount[b], (int)h);
  }
}

// ---- bucket scan + cursor init + rowptr sentinel ----
__global__ __launch_bounds__(512) void k_bscan(const int* __restrict__ gcount,
    int* __restrict__ gbase, int* __restrict__ gcursor, int* __restrict__ rowptr){
  __shared__ int s[512];
  int t = threadIdx.x;
  int v = (t<NBK)? gcount[t] : 0;
  s[t]=v; __syncthreads();
  for (int off=1; off<512; off<<=1){
    int u = (t>=off)? s[t-off]:0; __syncthreads();
    s[t]+=u; __syncthreads();
  }
  if (t<NBK){ int e = s[t]-v; gbase[t]=e; gcursor[t]=e; }
  if (t==NBK) gbase[NBK]=N_EDGES;
  if (t==0) rowptr[N_NODES]=N_EDGES;
}

// ---- partition: scatter packed (eid | dlow<<21) into bucket regions ----
__global__ __launch_bounds__(512) void k_part(const int* __restrict__ dst,
    int* __restrict__ gcursor, unsigned* __restrict__ part){
  __shared__ unsigned hist[NBK];
  __shared__ int bbase[NBK];
  __shared__ unsigned cur[NBK];
  int t = threadIdx.x;
  for (int b=t; b<NBK; b+=512) hist[b]=0;
  __syncthreads();
  int base = blockIdx.x * CHK;
  for (int i=t; i<CHK; i+=512) atomicAdd(&hist[dst[base+i]>>8], 1u);
  __syncthreads();
  for (int b=t; b<NBK; b+=512){
    unsigned h = hist[b];
    bbase[b] = h ? atomicAdd(&gcursor[b], (int)h) : 0;
    cur[b]=0;
  }
  __syncthreads();
  for (int i=t; i<CHK; i+=512){
    int e = base+i;
    int d = dst[e];
    int bin = d>>8;
    unsigned off = atomicAdd(&cur[bin], 1u);
    part[bbase[bin]+(int)off] = (unsigned)e | ((unsigned)(d&255)<<21);  // eid<2^21
  }
}

// ---- build_a: per-bucket per-quarter histograms -> rowptr + qpre bases ----
__global__ __launch_bounds__(512) void k_build_a(const int* __restrict__ gbase,
    const unsigned* __restrict__ part, int* __restrict__ rowptr, int* __restrict__ qpre){
  __shared__ unsigned cntq[4][256];
  __shared__ unsigned s[256];
  int t = threadIdx.x;
  int b = blockIdx.x;
  int lo = gbase[b], hi = gbase[b+1];
  int len = hi - lo;
  int q1 = lo + ((len*1)>>2), q2 = lo + ((len*2)>>2), q3 = lo + ((len*3)>>2);
  for (int k=t; k<1024; k+=512) ((unsigned*)cntq)[k] = 0u;
  __syncthreads();
  for (int i=lo+t; i<hi; i+=512){
    unsigned p = part[i];
    int node = (int)(p >> 21);
    int q = (i>=q1) + (i>=q2) + (i>=q3);
    atomicAdd(&cntq[q][node], 1u);
  }
  __syncthreads();
  unsigned tot = 0;
  if (t<256){ tot = cntq[0][t]+cntq[1][t]+cntq[2][t]+cntq[3][t]; s[t]=tot; }
  __syncthreads();
  for (int off=1; off<256; off<<=1){
    unsigned u = 0;
    if (t<256 && t>=off) u = s[t-off];
    __syncthreads();
    if (t<256) s[t]+=u;
    __syncthreads();
  }
  if (t<256){
    int rb = lo + (int)(s[t]-tot);
    int node = (b<<8)+t;
    if (node < N_NODES) rowptr[node]=rb;
    int run = rb;
    #pragma unroll
    for (int q=0;q<4;q++){
      qpre[((b*4+q)<<8) + t] = run;
      run += (int)cntq[q][t];
    }
  }
}

// ---- fill: one bucket-quarter per block; gather 8B ae01 + 4B src ----
__global__ __launch_bounds__(256) void k_fill(const int* __restrict__ gbase,
    const unsigned* __restrict__ part, const int* __restrict__ src,
    const float2* __restrict__ ae01, const int* __restrict__ qpre,
    uint4* __restrict__ csr){
  __shared__ unsigned cur[256];
  int t = threadIdx.x;
  int bq = blockIdx.x;
  int b = bq >> 2, q = bq & 3;
  int lo = gbase[b], hi = gbase[b+1];
  int len = hi - lo;
  int ql = lo + ((len*q)>>2);
  int qh = lo + ((len*(q+1))>>2);
  cur[t] = (unsigned)qpre[(bq<<8) + t];
  __syncthreads();
  for (int i = ql + t; i < qh; i += 512){
    int i1 = i + 256;
    bool has1 = i1 < qh;
    unsigned p0 = part[i];
    unsigned p1 = has1 ? part[i1] : p0;
    int e0 = (int)(p0 & 0x1FFFFFu), n0 = (int)(p0 >> 21);
    int e1 = (int)(p1 & 0x1FFFFFu), n1 = (int)(p1 >> 21);
    float2 ae_a = ae01[e0];
    float2 ae_b = ae01[e1];
    int s0 = src[e0], s1 = src[e1];
    unsigned o0 = atomicAdd(&cur[n0], 1u);
    csr[o0] = make_uint4((unsigned)s0, __float_as_uint(ae_a.x), __float_as_uint(ae_a.y), 0u);
    if (has1){
      unsigned o1 = atomicAdd(&cur[n1], 1u);
      csr[o1] = make_uint4((unsigned)s1, __float_as_uint(ae_b.x), __float_as_uint(ae_b.y), 0u);
    }
  }
}

// ---------------- fp32 GEMM + optional fused attention dots ----------------
__global__ __launch_bounds__(256) void k_gemm(const float* __restrict__ X, const float* __restrict__ W,
    const float* __restrict__ bias, float* __restrict__ Y, unsigned short* __restrict__ Ybf,
    const float* __restrict__ a_s, const float* __restrict__ a_d,
    float* __restrict__ asrc, float* __restrict__ adst, int M, int relu){
  __shared__ float Xs[16][68];
  __shared__ float Ws[16][128];
  __shared__ float as_s[128], ad_s[128];
  int t = threadIdx.x;
  if (a_s && t < 128){ as_s[t] = a_s[t]; ad_s[t] = a_d[t]; }
  int row0 = blockIdx.x * 64;
  int tc = t & 15, tr = t >> 4;
  int c0 = tc*8, r0 = tr*4;
  int lr = t >> 2, lc = (t & 3) << 2;
  int wk = t >> 4, wc = (t & 15) * 8;
  float acc[4][8];
  #pragma unroll
  for (int i=0;i<4;i++)
    #pragma unroll
    for (int j=0;j<8;j++) acc[i][j]=0.f;
  int gr = row0 + lr;
  for (int k0=0; k0<128; k0+=16){
    float4 xv = make_float4(0.f,0.f,0.f,0.f);
    if (gr < M) xv = *(const float4*)(X + (size_t)gr*128 + k0 + lc);
    float4 wv0 = *(const float4*)(W + (size_t)(k0+wk)*128 + wc);
    float4 wv1 = *(const float4*)(W + (size_t)(k0+wk)*128 + wc + 4);
    __syncthreads();
    Xs[lc+0][lr]=xv.x; Xs[lc+1][lr]=xv.y; Xs[lc+2][lr]=xv.z; Xs[lc+3][lr]=xv.w;
    *(float4*)&Ws[wk][wc]   = wv0;
    *(float4*)&Ws[wk][wc+4] = wv1;
    __syncthreads();
    #pragma unroll
    for (int kk=0;kk<16;kk++){
      float4 a  = *(const float4*)&Xs[kk][r0];
      float4 b0 = *(const float4*)&Ws[kk][c0];
      float4 b1 = *(const float4*)&Ws[kk][c0+4];
      float av[4] = {a.x,a.y,a.z,a.w};
      float bv[8] = {b0.x,b0.y,b0.z,b0.w,b1.x,b1.y,b1.z,b1.w};
      #pragma unroll
      for (int i=0;i<4;i++)
        #pragma unroll
        for (int j=0;j<8;j++) acc[i][j] += av[i]*bv[j];
    }
  }
  #pragma unroll
  for (int i=0;i<4;i++){
    int r = row0 + r0 + i;
    float v[8];
    #pragma unroll
    for (int j=0;j<8;j++){
      float u = acc[i][j] + (bias ? bias[c0+j] : 0.f);
      v[j] = relu ? fmaxf(u, 0.f) : u;
    }
    if (r < M){
      if (Y){
        *(float4*)(Y + (size_t)r*128 + c0)     = make_float4(v[0],v[1],v[2],v[3]);
        *(float4*)(Y + (size_t)r*128 + c0 + 4) = make_float4(v[4],v[5],v[6],v[7]);
      }
      if (Ybf){
        uint4 pk;
        pk.x = (unsigned)f2bf(v[0]) | ((unsigned)f2bf(v[1])<<16);
        pk.y = (unsigned)f2bf(v[2]) | ((unsigned)f2bf(v[3])<<16);
        pk.z = (unsigned)f2bf(v[4]) | ((unsigned)f2bf(v[5])<<16);
        pk.w = (unsigned)f2bf(v[6]) | ((unsigned)f2bf(v[7])<<16);
        *(uint4*)(Ybf + (size_t)r*128 + c0) = pk;
      }
    }
    if (a_s){
      float s=0.f, d=0.f;
      #pragma unroll
      for (int j=0;j<8;j++){ s += v[j]*as_s[c0+j]; d += v[j]*ad_s[c0+j]; }
      #pragma unroll
      for (int off=1; off<16; off<<=1){ s += __shfl_xor(s,off); d += __shfl_xor(d,off); }
      if ((t & 15)==0 && r < M){ asrc[r]=s; adst[r]=d; }
    }
  }
}

// ---------------- GAT aggregation: wave per node ----------------
// R16: online softmax — pass B eliminated. Pass A keeps running (m,p):
// per 64-edge chunk, max-reduce then register-resident exp-sum with rescale
// p = p*exp(m_old-m_new) + sum(exp(av-m_new)); self-loop folds via one
// final rescale. eb.x stores RAW alpha; pass C computes exp(av-m) inline
// (~4 transcendentals/thread). Also: no __syncthreads — eb[w] is
// wave-private, same-wave LDS ordering is lgkmcnt-guaranteed, so the 4
// waves of a block no longer lockstep on the slowest-deg node.
__global__ __launch_bounds__(256) void k_agg(const int* __restrict__ rowptr, const uint4* __restrict__ csr,
    const float* __restrict__ asrc, const float* __restrict__ adst,
    const unsigned short* __restrict__ xlbf,
    const float* __restrict__ bias, float* __restrict__ out, int relu, int layer){
  int w = threadIdx.x >> 6;
  int lane = threadIdx.x & 63;
  int n = blockIdx.x * WPB + w;          // grid exact
  __shared__ float2 eb[WPB][MAXDEG];     // {raw alpha, byteoff bits}
  const char* xbase = (const char*)xlbf; // row = 256 B
  int s0 = rowptr[n], s1 = rowptr[n+1];
  int deg = s1 - s0;
  float adst_n = adst[n];
  // pass A: alpha + online max / denom (register-resident, no LDS pass B)
  float m_e = -1e30f;
  float p = 0.f;
  float sae = 0.f;
  for (int base=0; base<deg; base+=64){
    int i = base + lane;
    float a = -1e30f;
    if (i < deg){
      uint4 p4 = csr[s0 + i];
      int sx = (int)p4.x;
      float ae = __uint_as_float(layer ? p4.z : p4.y);
      float av = lrelu(asrc[sx] + adst_n + ae);
      if (i < MAXDEG) eb[w][i] = make_float2(av, __uint_as_float((unsigned)sx << 8));
      a = av;
      sae += ae;
    }
    float am = a;
    for (int off=32; off; off>>=1) am = fmaxf(am, __shfl_xor(am, off));
    float mn = fmaxf(m_e, am);
    float ev = (i < deg) ? __expf(a - mn) : 0.f;
    for (int off=32; off; off>>=1) ev += __shfl_xor(ev, off);
    p = p * __expf(m_e - mn) + ev;    // first chunk: 0 * exp(-inf) = 0
    m_e = mn;
  }
  for (int off=32; off; off>>=1) sae += __shfl_xor(sae, off);
  float aloop_n = sae / fmaxf((float)deg, 1.f);
  float al = lrelu(asrc[n] + adst_n + aloop_n);   // self-loop alpha
  float m = fmaxf(m_e, al);
  float wl = __expf(al - m);
  float denom = p * __expf(m_e - m) + wl;         // deg=0: 0*0 + 1 = 1
  // pass C: 4-wide weighted gather of bf16 rows (exp computed inline)
  int g = lane >> 4, cl = lane & 15;
  unsigned clb = (unsigned)(cl << 4);
  float acc[8];
  #pragma unroll
  for (int j=0;j<8;j++) acc[j]=0.f;
  if (g == 0){
    uint4 v = *(const uint4*)(xbase + (((unsigned)n << 8) + clb));
    unsigned int uu[4] = {v.x,v.y,v.z,v.w};
    #pragma unroll
    for (int q=0;q<4;q++){
      acc[2*q]   += wl * __uint_as_float(uu[q] << 16);
      acc[2*q+1] += wl * __uint_as_float(uu[q] & 0xFFFF0000u);
    }
  }
  if (deg <= MAXDEG){
    int dfull = deg & ~7;
    for (int i=0; i<dfull; i+=8){      // unguarded main body
      float2 e0 = eb[w][i+g];
      float2 e1 = eb[w][i+4+g];
      float we0 = __expf(e0.x - m);
      float we1 = __expf(e1.x - m);
      uint4 v0 = *(const uint4*)(xbase + (__float_as_uint(e0.y) + clb));
      uint4 v1 = *(const uint4*)(xbase + (__float_as_uint(e1.y) + clb));
      unsigned int uu0[4] = {v0.x,v0.y,v0.z,v0.w};
      unsigned int uu1[4] = {v1.x,v1.y,v1.z,v1.w};
      #pragma unroll
      for (int q=0;q<4;q++){
        acc[2*q]   += we0 * __uint_as_float(uu0[q] << 16);
        acc[2*q+1] += we0 * __uint_as_float(uu0[q] & 0xFFFF0000u);
      }
      #pragma unroll
      for (int q=0;q<4;q++){
        acc[2*q]   += we1 * __uint_as_float(uu1[q] << 16);
        acc[2*q+1] += we1 * __uint_as_float(uu1[q] & 0xFFFF0000u);
      }
    }
    for (int i=dfull; i<deg; i+=4){    // guarded tail (<8 edges)
      int idx = i + g;
      float we = 0.f; unsigned off = (unsigned)n << 8;
      if (idx < deg){ float2 e = eb[w][idx]; we = __expf(e.x - m); off = __float_as_uint(e.y); }
      uint4 v = *(const uint4*)(xbase + (off + clb));
      unsigned int uu[4] = {v.x,v.y,v.z,v.w};
      #pragma unroll
      for (int q=0;q<4;q++){
        acc[2*q]   += we * __uint_as_float(uu[q] << 16);
        acc[2*q+1] += we * __uint_as_float(uu[q] & 0xFFFF0000u);
      }
    }
  } else {
    for (int i=0; i<deg; i+=8){
      int idx0 = i + g, idx1 = i + 4 + g;
      int sx0 = n, sx1 = n; float we0 = 0.f, we1 = 0.f;
      if (idx0 < deg){
        if (idx0 < MAXDEG){ float2 e = eb[w][idx0]; we0 = __expf(e.x - m); sx0 = (int)(__float_as_uint(e.y) >> 8); }
        else { uint4 p4 = csr[s0+idx0]; sx0 = (int)p4.x;
               we0 = __expf(lrelu(asrc[sx0] + adst_n + __uint_as_float(layer ? p4.z : p4.y)) - m); }
      }
      if (idx1 < deg){
        if (idx1 < MAXDEG){ float2 e = eb[w][idx1]; we1 = __expf(e.x - m); sx1 = (int)(__float_as_uint(e.y) >> 8); }
        else { uint4 p4 = csr[s0+idx1]; sx1 = (int)p4.x;
               we1 = __expf(lrelu(asrc[sx1] + adst_n + __uint_as_float(layer ? p4.z : p4.y)) - m); }
      }
      uint4 v0 = *(const uint4*)(xbase + (((unsigned)sx0 << 8) + clb));
      uint4 v1 = *(const uint4*)(xbase + (((unsigned)sx1 << 8) + clb));
      unsigned int uu0[4] = {v0.x,v0.y,v0.z,v0.w};
      unsigned int uu1[4] = {v1.x,v1.y,v1.z,v1.w};
      #pragma unroll
      for (int q=0;q<4;q++){
        acc[2*q]   += we0 * __uint_as_float(uu0[q] << 16);
        acc[2*q+1] += we0 * __uint_as_float(uu0[q] & 0xFFFF0000u);
      }
      #pragma unroll
      for (int q=0;q<4;q++){
        acc[2*q]   += we1 * __uint_as_float(uu1[q] << 16);
        acc[2*q+1] += we1 * __uint_as_float(uu1[q] & 0xFFFF0000u);
      }
    }
  }
  #pragma unroll
  for (int j=0;j<8;j++){
    acc[j] += __shfl_xor(acc[j], 16);
    acc[j] += __shfl_xor(acc[j], 32);
  }
  if (lane < 16){
    float inv = 1.f/denom;
    float4 b0 = *(const float4*)(bias + cl*8);
    float4 b1 = *(const float4*)(bias + cl*8 + 4);
    float o[8];
    o[0]=acc[0]*inv+b0.x; o[1]=acc[1]*inv+b0.y; o[2]=acc[2]*inv+b0.z; o[3]=acc[3]*inv+b0.w;
    o[4]=acc[4]*inv+b1.x; o[5]=acc[5]*inv+b1.y; o[6]=acc[6]*inv+b1.z; o[7]=acc[7]*inv+b1.w;
    if (relu){
      #pragma unroll
      for (int j=0;j<8;j++) o[j]=fmaxf(o[j],0.f);
    }
    *(float4*)(out + (size_t)n*128 + cl*8)     = make_float4(o[0],o[1],o[2],o[3]);
    *(float4*)(out + (size_t)n*128 + cl*8 + 4) = make_float4(o[4],o[5],o[6],o[7]);
  }
}

// ---------------- fused MLP: lin1 GEMM -> lin2 -> log_softmax ----------------
__global__ __launch_bounds__(256) void k_mlp(const float* __restrict__ X, const float* __restrict__ W,
    const float* __restrict__ bias, const float* __restrict__ w2, const float* __restrict__ b2,
    float* __restrict__ out, int M){
  __shared__ float Xs[16][68];
  __shared__ float Ws[16][128];
  __shared__ float b2s[16];
  int t = threadIdx.x;
  int row0 = blockIdx.x * 64;
  int tc = t & 15, tr = t >> 4;
  int c0 = tc*8, r0 = tr*4;
  int lr = t >> 2, lc = (t & 3) << 2;
  int wk = t >> 4, wc = (t & 15) * 8;
  float acc[4][8];
  #pragma unroll
  for (int i=0;i<4;i++)
    #pragma unroll
    for (int j=0;j<8;j++) acc[i][j]=0.f;
  int gr = row0 + lr;
  for (int k0=0; k0<128; k0+=16){
    float4 xv = make_float4(0.f,0.f,0.f,0.f);
    if (gr < M) xv = *(const float4*)(X + (size_t)gr*128 + k0 + lc);
    float4 wv0 = *(const float4*)(W + (size_t)(k0+wk)*128 + wc);
    float4 wv1 = *(const float4*)(W + (size_t)(k0+wk)*128 + wc + 4);
    __syncthreads();
    Xs[lc+0][lr]=xv.x; Xs[lc+1][lr]=xv.y; Xs[lc+2][lr]=xv.z; Xs[lc+3][lr]=xv.w;
    *(float4*)&Ws[wk][wc]   = wv0;
    *(float4*)&Ws[wk][wc+4] = wv1;
    __syncthreads();
    #pragma unroll
    for (int kk=0;kk<16;kk++){
      float4 a  = *(const float4*)&Xs[kk][r0];
      float4 b0 = *(const float4*)&Ws[kk][c0];
      float4 b1 = *(const float4*)&Ws[kk][c0+4];
      float av[4] = {a.x,a.y,a.z,a.w};
      float bv[8] = {b0.x,b0.y,b0.z,b0.w,b1.x,b1.y,b1.z,b1.w};
      #pragma unroll
      for (int i=0;i<4;i++)
        #pragma unroll
        for (int j=0;j<8;j++) acc[i][j] += av[i]*bv[j];
    }
  }
  __syncthreads();   // all Ws reads done before restage
  float* wflat = &Ws[0][0];   // w2 restaged here: wflat[col*16 + cls]
  #pragma unroll
  for (int i=0;i<2;i++) ((float4*)wflat)[t + i*256] = ((const float4*)w2)[t + i*256];
  if (t < 16) b2s[t] = b2[t];
  // h = relu(acc + l1b) in registers
  float4 bba = *(const float4*)(bias + c0);
  float4 bbb = *(const float4*)(bias + c0 + 4);
  float bb[8] = {bba.x,bba.y,bba.z,bba.w,bbb.x,bbb.y,bbb.z,bbb.w};
  #pragma unroll
  for (int i=0;i<4;i++)
    #pragma unroll
    for (int j=0;j<8;j++) acc[i][j] = fmaxf(acc[i][j] + bb[j], 0.f);
  __syncthreads();   // w2/b2 staged
  // ring-rotate lin2: conflict-free w2 reads (banks j*16+cls, cls distinct)
  float A0=0.f, A1=0.f, A2=0.f, A3=0.f;
  int sl = (tc+1) & 15;
  #pragma unroll 4
  for (int s=0; s<16; s++){
    int cls = (tc + s) & 15;
    const float* wp = wflat + (size_t)c0*16 + cls;
    float p0=0.f,p1=0.f,p2=0.f,p3=0.f;
    #pragma unroll
    for (int j=0;j<8;j++){
      float wv = wp[j*16];
      p0 += acc[0][j]*wv; p1 += acc[1][j]*wv; p2 += acc[2][j]*wv; p3 += acc[3][j]*wv;
    }
    A0+=p0; A1+=p1; A2+=p2; A3+=p3;
    A0=__shfl(A0,sl,16); A1=__shfl(A1,sl,16); A2=__shfl(A2,sl,16); A3=__shfl(A3,sl,16);
  }
  float A[4] = {A0,A1,A2,A3};
  float bcls = b2s[tc];
  #pragma unroll
  for (int i=0;i<4;i++){
    float v = A[i] + bcls;
    float m = v;
    #pragma unroll
    for (int off=1; off<16; off<<=1) m = fmaxf(m, __shfl_xor(m, off, 16));
    float ex = __expf(v - m);
    float sum = ex;
    #pragma unroll
    for (int off=1; off<16; off<<=1) sum += __shfl_xor(sum, off, 16);
    float lse = m + __logf(sum);
    int r = row0 + r0 + i;
    if (r < M) out[(size_t)r*16 + tc] = v - lse;
  }
}

extern "C" void kernel_launch(void* const* d_in, const int* in_sizes, int n_in,
                              void* d_out, int out_size, void* d_ws, size_t ws_size,
                              hipStream_t stream){
  const float* x    = (const float*)d_in[0];
  const float* eatt = (const float*)d_in[1];
  const float* W0   = (const float*)d_in[2];
  const float* as0  = (const float*)d_in[3];
  const float* ad0  = (const float*)d_in[4];
  const float* We0  = (const float*)d_in[5];
  const float* ae0  = (const float*)d_in[6];
  const float* b0   = (const float*)d_in[7];
  const float* W1   = (const float*)d_in[8];
  const float* as1  = (const float*)d_in[9];
  const float* ad1  = (const float*)d_in[10];
  const float* We1  = (const float*)d_in[11];
  const float* ae1  = (const float*)d_in[12];
  const float* b1   = (const float*)d_in[13];
  const float* l1w  = (const float*)d_in[14];
  const float* l1b  = (const float*)d_in[15];
  const float* l2w  = (const float*)d_in[16];
  const float* l2b  = (const float*)d_in[17];
  const int*   ei   = (const int*)d_in[18];
  const int* srcI = ei;
  const int* dstI = ei + N_EDGES;
  float* out = (float*)d_out;

  char* p = (char*)d_ws;
  auto alloc = [&](size_t bytes)->char*{ char* r = p; p += (bytes + 255) & ~255ull; return r; };
  unsigned short* Abf = (unsigned short*)alloc((size_t)N_NODES*128*2); // bf16 features
  float* B       = (float*)alloc((size_t)N_NODES*128*4);   // aggregation output
  float* asrc    = (float*)alloc((size_t)N_NODES*4);
  float* adst    = (float*)alloc((size_t)N_NODES*4);
  int* rowptr  = (int*)alloc((size_t)(N_NODES+1)*4);
  uint4* csr   = (uint4*)alloc((size_t)N_EDGES*16);
  int* gcount  = (int*)alloc(400*4);
  int* gbase   = (int*)alloc(400*4);
  int* gcursor = (int*)alloc(400*4);
  // part (6.4MB), qpre (1.6MB), ae01 (12.8MB) live in the B region: all
  // written and consumed strictly before agg0 overwrites B.
  char* Bc = (char*)B;
  unsigned* part = (unsigned*)Bc;                    // 6.4MB
  int*      qpre = (int*)(Bc + 6400000);             // 1.6MB (391*4*256*4)
  float2*   ae01 = (float2*)(Bc + 6400000 + 1602560);// 12.8MB, ends ~20.8MB < 51.2MB

  const int NB_W = N_NODES/WPB;         // 25000 (exact)
  const int NB_G = (N_NODES+63)/64;     // 1563

  // ---- preprocessing: 2-level bucket sort -> rowptr + csr ----
  hipMemsetAsync(gcount, 0, 400*4, stream);
  k_count<<<256,512,0,stream>>>(dstI, eatt, We0, ae0, We1, ae1, gcount, ae01);
  k_bscan<<<1,  512,0,stream>>>(gcount, gbase, gcursor, rowptr);
  k_part <<<256,512,0,stream>>>(dstI, gcursor, part);
  k_build_a<<<NBK,512,0,stream>>>(gbase, part, rowptr, qpre);
  // layer-0 GEMM (independent of preprocessing)
  k_gemm <<<NB_G,256,0,stream>>>(x, W0, nullptr, nullptr, Abf, as0, ad0, asrc, adst, N_NODES, 0);
  k_fill <<<NBK*4,256,0,stream>>>(gbase, part, srcI, ae01, qpre, csr);

  // ---- layer 0 aggregation ----
  k_agg  <<<NB_W,256,0,stream>>>(rowptr, csr, asrc, adst, Abf, b0, B, 1, 0);

  // ---- layer 1 ----
  k_gemm <<<NB_G,256,0,stream>>>(B, W1, nullptr, nullptr, Abf, as1, ad1, asrc, adst, N_NODES, 0);
  k_agg  <<<NB_W,256,0,stream>>>(rowptr, csr, asrc, adst, Abf, b1, B, 1, 1);

  // ---- post MLP (lin1 + lin2 + log_softmax fused) ----
  k_mlp  <<<NB_G,256,0,stream>>>(B, l1w, l1b, l2w, l2b, out, N_NODES);
}